// Round 19
// baseline (490.465 us; speedup 1.0000x reference)
//
#include <hip/hip_runtime.h>
#include <hip/hip_cooperative_groups.h>
#include <cstddef>
#include <cstdint>

namespace cg = cooperative_groups;

namespace {

using u16 = unsigned short;
typedef __attribute__((ext_vector_type(8))) unsigned short u16x8;
typedef __attribute__((ext_vector_type(8))) short bf16x8;
typedef __attribute__((ext_vector_type(4))) float f32x4;

constexpr int kN    = 10000;   // nodes
constexpr int kE    = 160000;  // edges
constexpr int kD    = 512;     // feature dim
constexpr int kNinv = 4000;
constexpr int kNunk = 3000;
constexpr int kND   = kN * kD;
constexpr int kScanBlocks = (kN + 255) / 256;  // 40
constexpr int kCsrGrid = 256;                  // cooperative grid (1 blk/CU)
constexpr float kLnEps = 1e-5f;

__device__ __forceinline__ float bf2f(u16 u) {
  return __uint_as_float((unsigned)u << 16);
}
__device__ __forceinline__ u16 f2bf(float f) {
  unsigned u = __float_as_uint(f);
  return (u16)((u + 0x7FFFu + ((u >> 16) & 1u)) >> 16);  // RNE
}

__device__ __forceinline__ void gload_lds16(const void* g, void* l) {
  __builtin_amdgcn_global_load_lds(
      (const __attribute__((address_space(1))) void*)(unsigned long long)(uintptr_t)g,
      (__attribute__((address_space(3))) void*)(unsigned)(uintptr_t)l,
      16, 0, 0);
}

// second job for merged dual-GEMM dispatches; xSplit = #x-blocks of job 0
struct Job2 {
  const u16* A1; const u16* A2; const u16* BT; const float* bias;
  u16* Cb; int M; int xSplit;
};

// ---------------------------------------------------------------------------
// bf16 MFMA GEMM: C[M,N] = A[M,K] * BT[N,K]^T (+ bias)
// (R11: operand-swap packed epilogue + XCD-bijective swizzle)
// A_F32: A fp32, reg-staged (2xfloat4 -> RNE bf16 -> same swizzled LDS slot).
// Job2: blocks with bx >= xSplit run the second job.
// ---------------------------------------------------------------------------
template <bool WRITE_F32, bool WRITE_BF16, bool A_F32>
__global__ __launch_bounds__(256) void gemm_bf16(
    const u16* __restrict__ A1, const u16* __restrict__ A2,
    const u16* __restrict__ BT, const float* __restrict__ bias,
    float* __restrict__ Cf, u16* __restrict__ Cb, u16* __restrict__ Cb2,
    int nsplit, int M, int N, int K, int ldc, Job2 j2) {
  __shared__ u16 As[128 * 64];  // 16 KB
  __shared__ u16 Bs[128 * 64];  // 16 KB
  const int tid  = threadIdx.x;
  const int lane = tid & 63;
  const int wid  = tid >> 6;

  // ---- XCD-bijective swizzle over the linear block id (m204)
  const int nwg = gridDim.x * gridDim.y;
  int wg = blockIdx.x + gridDim.x * blockIdx.y;
  {
    const int xcd = wg & 7, idx = wg >> 3;
    const int q = nwg >> 3, r = nwg & 7;
    wg = (xcd < r ? xcd * (q + 1) : r * (q + 1) + (xcd - r) * q) + idx;
  }
  int bx = wg % gridDim.x;
  const int ny = wg / gridDim.x;

  // ---- job select
  const u16* jA1 = A1; const u16* jA2 = A2; const u16* jBT = BT;
  const float* jbias = bias; u16* jCb = Cb; int jM = M;
  if (bx >= j2.xSplit) {
    bx -= j2.xSplit;
    jA1 = j2.A1; jA2 = j2.A2; jBT = j2.BT;
    jbias = j2.bias; jCb = j2.Cb; jM = j2.M;
  }
  const int bm = bx * 128;
  const int bn = ny * 128;

  const int wr = (wid >> 1) * 64;
  const int wc = (wid & 1) * 64;

  f32x4 acc[4][4];
#pragma unroll
  for (int m = 0; m < 4; ++m)
#pragma unroll
    for (int n = 0; n < 4; ++n) acc[m][n] = (f32x4){0.f, 0.f, 0.f, 0.f};

  const int srow = lane >> 3;  // 0..7
  const int slot = lane & 7;   // 16B slot in 128B row
  const size_t astride = (jA2 != nullptr) ? 512 : (size_t)K;

  for (int k0 = 0; k0 < K; k0 += 64) {
    const u16* Ap = jA1;
    int kof = k0;
    if (jA2 != nullptr && k0 >= 512) { Ap = jA2; kof = k0 - 512; }
#pragma unroll
    for (int t = 0; t < 4; ++t) {
      const int inst = wid * 4 + t;
      const int row  = inst * 8 + srow;
      const int scol = ((slot ^ (row & 7)) << 4);    // byte offset in bf16 row
      const int ar   = min(bm + row, jM - 1);
      if constexpr (A_F32) {
        const float* srcf = (const float*)Ap + (size_t)ar * astride + kof + (scol >> 1);
        const float4 v0 = *reinterpret_cast<const float4*>(srcf);
        const float4 v1 = *reinterpret_cast<const float4*>(srcf + 4);
        u16x8 pk;
        pk[0] = f2bf(v0.x); pk[1] = f2bf(v0.y); pk[2] = f2bf(v0.z); pk[3] = f2bf(v0.w);
        pk[4] = f2bf(v1.x); pk[5] = f2bf(v1.y); pk[6] = f2bf(v1.z); pk[7] = f2bf(v1.w);
        *reinterpret_cast<u16x8*>((char*)As + inst * 1024 + lane * 16) = pk;
      } else {
        gload_lds16((const char*)Ap + ((size_t)ar * astride + kof) * 2 + scol,
                    (char*)As + inst * 1024);
      }
    }
#pragma unroll
    for (int t = 0; t < 4; ++t) {
      const int inst = wid * 4 + t;
      const int row  = inst * 8 + srow;
      const int scol = ((slot ^ (row & 7)) << 4);
      const int bc   = min(bn + row, N - 1);
      gload_lds16((const char*)jBT + ((size_t)bc * K + k0) * 2 + scol,
                  (char*)Bs + inst * 1024);
    }
    asm volatile("s_waitcnt vmcnt(0)" ::: "memory");
    __syncthreads();

#pragma unroll
    for (int kk = 0; kk < 2; ++kk) {
      bf16x8 af[4], bfr[4];
#pragma unroll
      for (int m = 0; m < 4; ++m) {
        const int r = wr + m * 16 + (lane & 15);
        const int s = kk * 4 + (lane >> 4);
        af[m] = *(const bf16x8*)((const char*)As + r * 128 + ((s ^ (r & 7)) << 4));
      }
#pragma unroll
      for (int n = 0; n < 4; ++n) {
        const int c = wc + n * 16 + (lane & 15);
        const int s = kk * 4 + (lane >> 4);
        bfr[n] = *(const bf16x8*)((const char*)Bs + c * 128 + ((s ^ (c & 7)) << 4));
      }
      // operand-swapped: accumulates the C^T fragment (same sums, new layout)
#pragma unroll
      for (int m = 0; m < 4; ++m)
#pragma unroll
        for (int n = 0; n < 4; ++n)
          acc[m][n] = __builtin_amdgcn_mfma_f32_16x16x32_bf16(bfr[n], af[m],
                                                              acc[m][n], 0, 0, 0);
    }
    __syncthreads();
  }

  // ---- epilogue: thread holds C[r, c0..c0+3]
#pragma unroll
  for (int m = 0; m < 4; ++m) {
    const int r = bm + wr + m * 16 + (lane & 15);
    if (r >= jM) continue;
#pragma unroll
    for (int n = 0; n < 4; ++n) {
      const int c0 = bn + wc + n * 16 + ((lane >> 4) << 2);
      if (c0 >= N) continue;  // N%4==0 -> whole 4-pack in range
      float4 bv = make_float4(0.f, 0.f, 0.f, 0.f);
      if (jbias != nullptr) bv = *reinterpret_cast<const float4*>(jbias + c0);
      float v0 = acc[m][n][0] + bv.x;
      float v1 = acc[m][n][1] + bv.y;
      float v2 = acc[m][n][2] + bv.z;
      float v3 = acc[m][n][3] + bv.w;
      if (WRITE_F32) {
        float4 o; o.x = v0; o.y = v1; o.z = v2; o.w = v3;
        *reinterpret_cast<float4*>(Cf + (size_t)r * ldc + c0) = o;
      }
      if (WRITE_BF16) {
        u16* dstp = jCb;
        int c = c0;
        if (Cb2 != nullptr && c0 >= nsplit) { dstp = Cb2; c = c0 - nsplit; }
        ushort4 o;
        o.x = f2bf(v0); o.y = f2bf(v1); o.z = f2bf(v2); o.w = f2bf(v3);
        *reinterpret_cast<ushort4*>(dstp + (size_t)r * ldc + c) = o;
      }
    }
  }
}

// ---------------------------------------------------------------------------
// Fused per-node GATv2 attention + residual + LayerNorm + ReLU.
// (R15/R17 kernel, verbatim — best measured: 65.2 us.)
// ---------------------------------------------------------------------------
__global__ __launch_bounds__(256) void gat_fused_kernel(
    const u16* __restrict__ xl, const u16* __restrict__ xr,
    const int* __restrict__ esrcS, const float2* __restrict__ eaS,
    const int* __restrict__ offs, const float* __restrict__ We,
    const float* __restrict__ att, const float* __restrict__ bias,
    const float* __restrict__ lng, const float* __restrict__ lnb,
    const u16* __restrict__ resid, u16* __restrict__ hb) {
  __shared__ float accLDS[4][512];
  __shared__ float wsLDS[4];
  const int wid = threadIdx.x >> 6, lane = threadIdx.x & 63;
  const int n = blockIdx.x;
  const int d8 = lane * 8;

  float r8[8], w0[8], w1[8], a06[8], a04[8];
  {
    const u16x8 rv = *(const u16x8*)(xr + (size_t)n * kD + d8);
#pragma unroll
    for (int i = 0; i < 8; ++i) {
      r8[i] = bf2f(rv[i]);
      w0[i] = We[d8 + i];
      w1[i] = We[kD + d8 + i];
      const float a = att[d8 + i];
      a06[i] = 0.6f * a;      // lrelu(m) = 0.6m + 0.4|m| for slope 0.2
      a04[i] = 0.4f * a;
    }
  }

  float acc[8];
#pragma unroll
  for (int j = 0; j < 8; ++j) acc[j] = 0.f;
  float l_run = 0.f;

  const int beg = offs[n], end = offs[n + 1];
  const int cnt = end - beg;
  const int q = cnt >> 2, r = cnt & 3;
  const int myCnt = q + ((wid < r) ? 1 : 0);
  const int myBeg = beg + wid * q + min(wid, r);

  int sv = 0;
  float2 e2 = make_float2(0.f, 0.f);
  if (lane < myCnt) {
    sv = esrcS[myBeg + lane];
    e2 = eaS[myBeg + lane];
  }

  for (int i = 0; i < myCnt; i += 4) {
    const int k = myCnt - i;  // wave-uniform guards
    u16x8 rows[4];
#pragma unroll
    for (int t = 0; t < 4; ++t)
      if (t < k)
        rows[t] = *(const u16x8*)(xl + (size_t)__shfl(sv, i + t) * kD + d8);
    float s[4];
#pragma unroll
    for (int t = 0; t < 4; ++t) {
      s[t] = 0.f;
      if (t < k) {
        const float ex = __shfl(e2.x, i + t), ey = __shfl(e2.y, i + t);
#pragma unroll
        for (int j = 0; j < 8; ++j) {
          const float m = bf2f(rows[t][j]) + r8[j] + ex * w0[j] + ey * w1[j];
          s[t] += a06[j] * m + a04[j] * fabsf(m);
        }
      }
    }
#pragma unroll
    for (int off = 32; off > 0; off >>= 1)
#pragma unroll
      for (int t = 0; t < 4; ++t)
        if (t < k) s[t] += __shfl_xor(s[t], off);
    float qv[4];
    float ws = 0.f;
#pragma unroll
    for (int t = 0; t < 4; ++t) {
      qv[t] = (t < k) ? __expf(s[t]) : 0.f;
      ws += qv[t];
    }
    l_run += ws;
#pragma unroll
    for (int j = 0; j < 8; ++j) {
      float v = acc[j];
#pragma unroll
      for (int t = 0; t < 4; ++t)
        if (t < k) v += qv[t] * bf2f(rows[t][j]);
      acc[j] = v;
    }
  }

  if (lane == 0) wsLDS[wid] = l_run;
#pragma unroll
  for (int j = 0; j < 8; ++j) accLDS[wid][j * 64 + lane] = acc[j];
  __syncthreads();

  if (wid == 0) {
    const float l = wsLDS[0] + wsLDS[1] + wsLDS[2] + wsLDS[3];
    const float inv = 1.f / (l > 0.f ? l : 1.f);
    float aT[8];
#pragma unroll
    for (int j = 0; j < 8; ++j)
      aT[j] = accLDS[0][j * 64 + lane] + accLDS[1][j * 64 + lane] +
              accLDS[2][j * 64 + lane] + accLDS[3][j * 64 + lane];

    float xv[8];
    float sum = 0.f, sq = 0.f;
    {
      const u16x8 hv8 = *(const u16x8*)(resid + (size_t)n * kD + d8);
#pragma unroll
      for (int j = 0; j < 8; ++j) {
        xv[j] = bf2f(hv8[j]) + aT[j] * inv + bias[d8 + j];
        sum += xv[j];
        sq  += xv[j] * xv[j];
      }
    }
#pragma unroll
    for (int off = 32; off > 0; off >>= 1) {
      sum += __shfl_xor(sum, off);
      sq  += __shfl_xor(sq, off);
    }
    const float mean = sum * (1.f / kD);
    const float var  = sq * (1.f / kD) - mean * mean;
    const float rs = rsqrtf(var + kLnEps);
    u16x8 pk;
#pragma unroll
    for (int j = 0; j < 8; ++j) {
      const float y = fmaxf((xv[j] - mean) * rs * lng[d8 + j] + lnb[d8 + j], 0.f);
      pk[j] = f2bf(y);
    }
    *(u16x8*)(hb + (size_t)n * kD + d8) = pk;
  }
}

// ---------------------------------------------------------------------------
// Batched transpose (z<10): dst[n][k] = bf16(src[k][n]); N=512 cols each.
// z==10: concat bias build (counts zeroing moved to the coop CSR kernel).
// ---------------------------------------------------------------------------
struct TxJobs {
  const float* src[10];
  u16* dst[10];
  int K[10];
  const float* bl; const float* br; float* catB;
};

__global__ __launch_bounds__(256) void transpose_all_kernel(TxJobs jobs) {
  const int z = blockIdx.z;
  if (z == 10) {
    const int lid = (blockIdx.y * 32 + blockIdx.x) * 256 + threadIdx.x;
    if (lid < 3 * 1024) {
      const int k = lid >> 10, j = lid & 1023;
      jobs.catB[lid] = (j < 512) ? jobs.bl[k * 512 + j] : jobs.br[k * 512 + j - 512];
    }
    return;
  }
  const int K = jobs.K[z];
  const int k0 = blockIdx.x * 32;
  if (k0 >= K) return;
  const int n0 = blockIdx.y * 32;
  const float* W = jobs.src[z];
  u16* WT = jobs.dst[z];
  __shared__ float t[32][33];
  const int lx = threadIdx.x & 31, ly = threadIdx.x >> 5;  // 32 x 8
#pragma unroll
  for (int r = 0; r < 32; r += 8)
    t[ly + r][lx] = W[(size_t)(k0 + ly + r) * 512 + n0 + lx];
  __syncthreads();
#pragma unroll
  for (int r = 0; r < 32; r += 8)
    WT[(size_t)(n0 + ly + r) * K + k0 + lx] = f2bf(t[lx][ly + r]);
}

// ---------------------------------------------------------------------------
// Cooperative single-dispatch CSR build: zero -> count -> hierarchical scan
// -> scatter (replaces 5 dispatches; grid.sync() = ordering + device fence).
// ---------------------------------------------------------------------------
__global__ __launch_bounds__(256) void csr_coop_kernel(
    const int* __restrict__ dst, const int* __restrict__ src,
    const float* __restrict__ ea, int* __restrict__ counts,
    int* __restrict__ offs, int* __restrict__ pos, int* __restrict__ bsum,
    int* __restrict__ esrcS, float2* __restrict__ eaS) {
  cg::grid_group grid = cg::this_grid();
  const int tid = threadIdx.x, bid = blockIdx.x;
  const int gsz = kCsrGrid * 256, gid = bid * 256 + tid;

  // phase 0: zero counts
  for (int i = gid; i < kN; i += gsz) counts[i] = 0;
  grid.sync();
  // phase 1: count
  for (int e = gid; e < kE; e += gsz) atomicAdd(&counts[dst[e]], 1);
  grid.sync();
  // phase 2a: block-local exclusive scans (chunks 0..39)
  __shared__ int buf[256];
  if (bid < kScanBlocks) {
    const int i = bid * 256 + tid;
    const int v = (i < kN) ? counts[i] : 0;
    buf[tid] = v;
    __syncthreads();
    for (int off = 1; off < 256; off <<= 1) {
      const int t = (tid >= off) ? buf[tid - off] : 0;
      __syncthreads();
      buf[tid] += t;
      __syncthreads();
    }
    if (i < kN) offs[i] = buf[tid] - v;
    if (tid == 255) bsum[bid] = buf[255];
  }
  grid.sync();
  // phase 2b: top scan (block 0, one wave); bsum becomes boff in place
  if (bid == 0 && tid < 64) {
    const int v = (tid < kScanBlocks) ? bsum[tid] : 0;
    int incl = v;
#pragma unroll
    for (int off = 1; off < 64; off <<= 1) {
      const int t = __shfl_up(incl, off);
      if (tid >= off) incl += t;
    }
    if (tid < kScanBlocks) bsum[tid] = incl - v;
    if (tid == 63) offs[kN] = incl;
  }
  grid.sync();
  // phase 2c: add block offsets; seed pos
  if (bid < kScanBlocks) {
    const int i = bid * 256 + tid;
    if (i < kN) {
      const int o = offs[i] + bsum[bid];
      offs[i] = o;
      pos[i] = o;
    }
  }
  grid.sync();
  // phase 3: scatter metadata into dst-sorted order
  for (int e = gid; e < kE; e += gsz) {
    const int p = atomicAdd(&pos[dst[e]], 1);
    esrcS[p] = src[e];
    eaS[p] = *(const float2*)(ea + (size_t)e * 2);
  }
}

}  // namespace

extern "C" void kernel_launch(void* const* d_in, const int* in_sizes, int n_in,
                              void* d_out, int out_size, void* d_ws, size_t ws_size,
                              hipStream_t stream) {
  const float* x         = (const float*)d_in[0];
  const float* edge_attr = (const float*)d_in[1];
  const float* emb_inv_W = (const float*)d_in[2];
  const float* emb_inv_b = (const float*)d_in[3];
  const float* emb_org_W = (const float*)d_in[4];
  const float* emb_org_b = (const float*)d_in[5];
  const float* gat_Wl    = (const float*)d_in[6];
  const float* gat_bl    = (const float*)d_in[7];
  const float* gat_Wr    = (const float*)d_in[8];
  const float* gat_br    = (const float*)d_in[9];
  const float* gat_We    = (const float*)d_in[10];
  const float* gat_att   = (const float*)d_in[11];
  const float* gat_bias  = (const float*)d_in[12];
  const float* ln_g      = (const float*)d_in[13];
  const float* ln_b      = (const float*)d_in[14];
  const float* lin0_W    = (const float*)d_in[15];
  const float* lin0_b    = (const float*)d_in[16];
  const float* lin1_W    = (const float*)d_in[17];
  const float* lin1_b    = (const float*)d_in[18];
  const int*   edge_idx  = (const int*)d_in[19];
  const int* src = edge_idx;
  const int* dst = edge_idx + kE;
  float* out = (float*)d_out;

  // ---- workspace layout (~58 MB) ----
  float* catB = (float*)d_ws;          // [3,1024] concat gat biases
  u16* hb0  = (u16*)(catB + 3072);     // [N,D] bf16 initial embedding (residual 0)
  u16* hb   = hb0 + kND;               // [N,D] bf16 running h (residual stream)
  u16* xlB  = hb + kND;                // [N,D]
  u16* xrB  = xlB + kND;               // [N,D]
  u16* y0b  = xrB + kND;               // [4000,512]
  u16* y1b  = y0b + kNinv * kD;        // [3000,512]
  u16* embInvT = y1b + kNunk * kD;     // [512,512]
  u16* embOrgT = embInvT + 262144;
  u16* WlrT    = embOrgT + 262144;     // 3 x [1024,512] (WlT rows 0-511, WrT 512-1023)
  u16* lin0T   = WlrT + 3 * 524288;    // [512,1024]
  u16* lin1T   = lin0T + 524288;
  int* counts  = (int*)(lin1T + 524288);  // [N]
  int* offs    = counts + kN;             // [N+1]
  int* pos     = offs + kN + 1;           // [N]
  int* bsum    = pos + kN;                // [kScanBlocks]
  int* esrcS   = bsum + kScanBlocks;      // [E] src in dst-sorted order
  float2* eaS  = (float2*)(esrcS + kE);   // [E] edge_attr in dst-sorted order

  const dim3 blk(256);
  auto cdiv = [](int a, int b) { return (a + b - 1) / b; };
  Job2 jNone{};
  jNone.xSplit = 0x7FFFFFFF;

  // ---- 0. setup: batched weight transpose + (z=10) catbias
  {
    TxJobs j;
    j.src[0] = emb_inv_W;  j.dst[0] = embInvT;  j.K[0] = 512;
    j.src[1] = emb_org_W;  j.dst[1] = embOrgT;  j.K[1] = 512;
    for (int k = 0; k < 3; ++k) {
      j.src[2 + k] = gat_Wl + (size_t)k * kD * kD;
      j.dst[2 + k] = WlrT + (size_t)k * 524288;            // rows 0..511
      j.K[2 + k] = 512;
      j.src[5 + k] = gat_Wr + (size_t)k * kD * kD;
      j.dst[5 + k] = WlrT + (size_t)k * 524288 + 262144;   // rows 512..1023
      j.K[5 + k] = 512;
    }
    j.src[8] = lin0_W; j.dst[8] = lin0T; j.K[8] = 1024;
    j.src[9] = lin1_W; j.dst[9] = lin1T; j.K[9] = 1024;
    j.bl = gat_bl; j.br = gat_br; j.catB = catB;
    transpose_all_kernel<<<dim3(32, 16, 11), blk, 0, stream>>>(j);
  }

  // ---- 1. CSR build in ONE cooperative dispatch
  {
    void* args[] = {(void*)&dst, (void*)&src, (void*)&edge_attr,
                    (void*)&counts, (void*)&offs, (void*)&pos, (void*)&bsum,
                    (void*)&esrcS, (void*)&eaS};
    hipLaunchCooperativeKernel((const void*)csr_coop_kernel, dim3(kCsrGrid), blk,
                               args, 0, stream);
  }

  // ---- 2. embeddings (merged pair; A = fp32 x reg-staged) -> hb0
  {
    Job2 je;
    je.A1 = (const u16*)(x + (size_t)kNinv * kD);
    je.A2 = nullptr;
    je.BT = embOrgT;
    je.bias = emb_org_b;
    je.Cb = hb0 + (size_t)kNinv * kD;
    je.M = kN - kNinv;
    je.xSplit = cdiv(kNinv, 128);  // 32
    const int gx = je.xSplit + cdiv(kN - kNinv, 128);  // 32 + 47
    gemm_bf16<false, true, true><<<dim3(gx, 4), blk, 0, stream>>>(
        (const u16*)x, nullptr, embInvT, emb_inv_b, nullptr, hb0, nullptr, 0,
        kNinv, kD, kD, kD, je);
  }

  // ---- 3. GAT layers: 1 fused lr-GEMM + 1 fused attention kernel each
  for (int k = 0; k < 3; ++k) {
    const u16* hIn = (k == 0) ? hb0 : hb;
    gemm_bf16<false, true, false><<<dim3(cdiv(kN, 128), 8), blk, 0, stream>>>(
        hIn, nullptr, WlrT + (size_t)k * 524288, catB + k * 1024,
        nullptr, xlB, xrB, 512, kN, 1024, kD, kD, jNone);
    gat_fused_kernel<<<dim3(kN), blk, 0, stream>>>(
        xlB, xrB, esrcS, eaS, offs,
        gat_We + (size_t)k * 2 * kD, gat_att + (size_t)k * kD,
        gat_bias + (size_t)k * kD, ln_g + (size_t)k * kD,
        ln_b + (size_t)k * kD, hIn, hb);
  }

  // ---- 4. heads (merged pair) via A-split ([hb0 | hb] along K): y0, y1
  {
    const size_t off = (size_t)(kN - kNunk) * kD;
    Job2 jh;
    jh.A1 = hb0 + off;
    jh.A2 = hb + off;
    jh.BT = lin1T;
    jh.bias = lin1_b;
    jh.Cb = y1b;
    jh.M = kNunk;
    jh.xSplit = cdiv(kNinv, 128);  // 32
    const int gx = jh.xSplit + cdiv(kNunk, 128);  // 32 + 24
    gemm_bf16<false, true, false><<<dim3(gx, 4), blk, 0, stream>>>(
        hb0, hb, lin0T, lin0_b, nullptr, y0b, nullptr, 0,
        kNinv, kD, 2 * kD, kD, jh);
  }

  // ---- 5. out = y0 @ y1^T  [4000,3000]
  gemm_bf16<true, false, false><<<dim3(cdiv(kNinv, 128), cdiv(kNunk, 128)), blk, 0,
                                  stream>>>(
      y0b, nullptr, y1b, nullptr, out, nullptr, nullptr, 0,
      kNinv, kNunk, kD, kNunk, jNone);
}

// Round 20
// 362.944 us; speedup vs baseline: 1.3514x; 1.3514x over previous
//
#include <hip/hip_runtime.h>
#include <cstddef>
#include <cstdint>

namespace {

using u16 = unsigned short;
typedef __attribute__((ext_vector_type(8))) unsigned short u16x8;
typedef __attribute__((ext_vector_type(8))) short bf16x8;
typedef __attribute__((ext_vector_type(4))) float f32x4;

constexpr int kN    = 10000;   // nodes
constexpr int kE    = 160000;  // edges
constexpr int kD    = 512;     // feature dim
constexpr int kNinv = 4000;
constexpr int kNunk = 3000;
constexpr int kND   = kN * kD;
constexpr int kScanBlocks = (kN + 255) / 256;  // 40
constexpr float kLnEps = 1e-5f;

__device__ __forceinline__ float bf2f(u16 u) {
  return __uint_as_float((unsigned)u << 16);
}
__device__ __forceinline__ u16 f2bf(float f) {
  unsigned u = __float_as_uint(f);
  return (u16)((u + 0x7FFFu + ((u >> 16) & 1u)) >> 16);  // RNE
}

__device__ __forceinline__ void gload_lds16(const void* g, void* l) {
  __builtin_amdgcn_global_load_lds(
      (const __attribute__((address_space(1))) void*)(unsigned long long)(uintptr_t)g,
      (__attribute__((address_space(3))) void*)(unsigned)(uintptr_t)l,
      16, 0, 0);
}

// second job for merged dual-GEMM dispatches; xSplit = #x-blocks of job 0
struct Job2 {
  const u16* A1; const u16* A2; const u16* BT; const float* bias;
  u16* Cb; int M; int xSplit;
};

// ---------------------------------------------------------------------------
// bf16 MFMA GEMM: C[M,N] = A[M,K] * BT[N,K]^T (+ bias)
// (R11: operand-swap packed epilogue + XCD-bijective swizzle)
// A_F32: A fp32, reg-staged (2xfloat4 -> RNE bf16 -> same swizzled LDS slot).
// Job2: blocks with bx >= xSplit run the second job.
// ---------------------------------------------------------------------------
template <bool WRITE_F32, bool WRITE_BF16, bool A_F32>
__global__ __launch_bounds__(256) void gemm_bf16(
    const u16* __restrict__ A1, const u16* __restrict__ A2,
    const u16* __restrict__ BT, const float* __restrict__ bias,
    float* __restrict__ Cf, u16* __restrict__ Cb, u16* __restrict__ Cb2,
    int nsplit, int M, int N, int K, int ldc, Job2 j2) {
  __shared__ u16 As[128 * 64];  // 16 KB
  __shared__ u16 Bs[128 * 64];  // 16 KB
  const int tid  = threadIdx.x;
  const int lane = tid & 63;
  const int wid  = tid >> 6;

  // ---- XCD-bijective swizzle over the linear block id (m204)
  const int nwg = gridDim.x * gridDim.y;
  int wg = blockIdx.x + gridDim.x * blockIdx.y;
  {
    const int xcd = wg & 7, idx = wg >> 3;
    const int q = nwg >> 3, r = nwg & 7;
    wg = (xcd < r ? xcd * (q + 1) : r * (q + 1) + (xcd - r) * q) + idx;
  }
  int bx = wg % gridDim.x;
  const int ny = wg / gridDim.x;

  // ---- job select
  const u16* jA1 = A1; const u16* jA2 = A2; const u16* jBT = BT;
  const float* jbias = bias; u16* jCb = Cb; int jM = M;
  if (bx >= j2.xSplit) {
    bx -= j2.xSplit;
    jA1 = j2.A1; jA2 = j2.A2; jBT = j2.BT;
    jbias = j2.bias; jCb = j2.Cb; jM = j2.M;
  }
  const int bm = bx * 128;
  const int bn = ny * 128;

  const int wr = (wid >> 1) * 64;
  const int wc = (wid & 1) * 64;

  f32x4 acc[4][4];
#pragma unroll
  for (int m = 0; m < 4; ++m)
#pragma unroll
    for (int n = 0; n < 4; ++n) acc[m][n] = (f32x4){0.f, 0.f, 0.f, 0.f};

  const int srow = lane >> 3;  // 0..7
  const int slot = lane & 7;   // 16B slot in 128B row
  const size_t astride = (jA2 != nullptr) ? 512 : (size_t)K;

  for (int k0 = 0; k0 < K; k0 += 64) {
    const u16* Ap = jA1;
    int kof = k0;
    if (jA2 != nullptr && k0 >= 512) { Ap = jA2; kof = k0 - 512; }
#pragma unroll
    for (int t = 0; t < 4; ++t) {
      const int inst = wid * 4 + t;
      const int row  = inst * 8 + srow;
      const int scol = ((slot ^ (row & 7)) << 4);    // byte offset in bf16 row
      const int ar   = min(bm + row, jM - 1);
      if constexpr (A_F32) {
        const float* srcf = (const float*)Ap + (size_t)ar * astride + kof + (scol >> 1);
        const float4 v0 = *reinterpret_cast<const float4*>(srcf);
        const float4 v1 = *reinterpret_cast<const float4*>(srcf + 4);
        u16x8 pk;
        pk[0] = f2bf(v0.x); pk[1] = f2bf(v0.y); pk[2] = f2bf(v0.z); pk[3] = f2bf(v0.w);
        pk[4] = f2bf(v1.x); pk[5] = f2bf(v1.y); pk[6] = f2bf(v1.z); pk[7] = f2bf(v1.w);
        *reinterpret_cast<u16x8*>((char*)As + inst * 1024 + lane * 16) = pk;
      } else {
        gload_lds16((const char*)Ap + ((size_t)ar * astride + kof) * 2 + scol,
                    (char*)As + inst * 1024);
      }
    }
#pragma unroll
    for (int t = 0; t < 4; ++t) {
      const int inst = wid * 4 + t;
      const int row  = inst * 8 + srow;
      const int scol = ((slot ^ (row & 7)) << 4);
      const int bc   = min(bn + row, N - 1);
      gload_lds16((const char*)jBT + ((size_t)bc * K + k0) * 2 + scol,
                  (char*)Bs + inst * 1024);
    }
    asm volatile("s_waitcnt vmcnt(0)" ::: "memory");
    __syncthreads();

#pragma unroll
    for (int kk = 0; kk < 2; ++kk) {
      bf16x8 af[4], bfr[4];
#pragma unroll
      for (int m = 0; m < 4; ++m) {
        const int r = wr + m * 16 + (lane & 15);
        const int s = kk * 4 + (lane >> 4);
        af[m] = *(const bf16x8*)((const char*)As + r * 128 + ((s ^ (r & 7)) << 4));
      }
#pragma unroll
      for (int n = 0; n < 4; ++n) {
        const int c = wc + n * 16 + (lane & 15);
        const int s = kk * 4 + (lane >> 4);
        bfr[n] = *(const bf16x8*)((const char*)Bs + c * 128 + ((s ^ (c & 7)) << 4));
      }
      // operand-swapped: accumulates the C^T fragment (same sums, new layout)
#pragma unroll
      for (int m = 0; m < 4; ++m)
#pragma unroll
        for (int n = 0; n < 4; ++n)
          acc[m][n] = __builtin_amdgcn_mfma_f32_16x16x32_bf16(bfr[n], af[m],
                                                              acc[m][n], 0, 0, 0);
    }
    __syncthreads();
  }

  // ---- epilogue: thread holds C[r, c0..c0+3]
#pragma unroll
  for (int m = 0; m < 4; ++m) {
    const int r = bm + wr + m * 16 + (lane & 15);
    if (r >= jM) continue;
#pragma unroll
    for (int n = 0; n < 4; ++n) {
      const int c0 = bn + wc + n * 16 + ((lane >> 4) << 2);
      if (c0 >= N) continue;  // N%4==0 -> whole 4-pack in range
      float4 bv = make_float4(0.f, 0.f, 0.f, 0.f);
      if (jbias != nullptr) bv = *reinterpret_cast<const float4*>(jbias + c0);
      float v0 = acc[m][n][0] + bv.x;
      float v1 = acc[m][n][1] + bv.y;
      float v2 = acc[m][n][2] + bv.z;
      float v3 = acc[m][n][3] + bv.w;
      if (WRITE_F32) {
        float4 o; o.x = v0; o.y = v1; o.z = v2; o.w = v3;
        *reinterpret_cast<float4*>(Cf + (size_t)r * ldc + c0) = o;
      }
      if (WRITE_BF16) {
        u16* dstp = jCb;
        int c = c0;
        if (Cb2 != nullptr && c0 >= nsplit) { dstp = Cb2; c = c0 - nsplit; }
        ushort4 o;
        o.x = f2bf(v0); o.y = f2bf(v1); o.z = f2bf(v2); o.w = f2bf(v3);
        *reinterpret_cast<ushort4*>(dstp + (size_t)r * ldc + c) = o;
      }
    }
  }
}

// ---------------------------------------------------------------------------
// Fused per-node GATv2 attention + residual + LayerNorm + ReLU.
// (R15/R17 kernel; only change: beg/end computed from offsL + boff on the
// fly — offs is never materialized.)
// ---------------------------------------------------------------------------
__global__ __launch_bounds__(256) void gat_fused_kernel(
    const u16* __restrict__ xl, const u16* __restrict__ xr,
    const int* __restrict__ esrcS, const float2* __restrict__ eaS,
    const int* __restrict__ offsL, const int* __restrict__ boff,
    const float* __restrict__ We,
    const float* __restrict__ att, const float* __restrict__ bias,
    const float* __restrict__ lng, const float* __restrict__ lnb,
    const u16* __restrict__ resid, u16* __restrict__ hb) {
  __shared__ float accLDS[4][512];
  __shared__ float wsLDS[4];
  const int wid = threadIdx.x >> 6, lane = threadIdx.x & 63;
  const int n = blockIdx.x;
  const int d8 = lane * 8;

  float r8[8], w0[8], w1[8], a06[8], a04[8];
  {
    const u16x8 rv = *(const u16x8*)(xr + (size_t)n * kD + d8);
#pragma unroll
    for (int i = 0; i < 8; ++i) {
      r8[i] = bf2f(rv[i]);
      w0[i] = We[d8 + i];
      w1[i] = We[kD + d8 + i];
      const float a = att[d8 + i];
      a06[i] = 0.6f * a;      // lrelu(m) = 0.6m + 0.4|m| for slope 0.2
      a04[i] = 0.4f * a;
    }
  }

  float acc[8];
#pragma unroll
  for (int j = 0; j < 8; ++j) acc[j] = 0.f;
  float l_run = 0.f;

  const int beg = offsL[n] + boff[n >> 8];
  const int end = (n == kN - 1) ? kE : (offsL[n + 1] + boff[(n + 1) >> 8]);
  const int cnt = end - beg;
  const int q = cnt >> 2, r = cnt & 3;
  const int myCnt = q + ((wid < r) ? 1 : 0);
  const int myBeg = beg + wid * q + min(wid, r);

  int sv = 0;
  float2 e2 = make_float2(0.f, 0.f);
  if (lane < myCnt) {
    sv = esrcS[myBeg + lane];
    e2 = eaS[myBeg + lane];
  }

  for (int i = 0; i < myCnt; i += 4) {
    const int k = myCnt - i;  // wave-uniform guards
    u16x8 rows[4];
#pragma unroll
    for (int t = 0; t < 4; ++t)
      if (t < k)
        rows[t] = *(const u16x8*)(xl + (size_t)__shfl(sv, i + t) * kD + d8);
    float s[4];
#pragma unroll
    for (int t = 0; t < 4; ++t) {
      s[t] = 0.f;
      if (t < k) {
        const float ex = __shfl(e2.x, i + t), ey = __shfl(e2.y, i + t);
#pragma unroll
        for (int j = 0; j < 8; ++j) {
          const float m = bf2f(rows[t][j]) + r8[j] + ex * w0[j] + ey * w1[j];
          s[t] += a06[j] * m + a04[j] * fabsf(m);
        }
      }
    }
#pragma unroll
    for (int off = 32; off > 0; off >>= 1)
#pragma unroll
      for (int t = 0; t < 4; ++t)
        if (t < k) s[t] += __shfl_xor(s[t], off);
    float qv[4];
    float ws = 0.f;
#pragma unroll
    for (int t = 0; t < 4; ++t) {
      qv[t] = (t < k) ? __expf(s[t]) : 0.f;
      ws += qv[t];
    }
    l_run += ws;
#pragma unroll
    for (int j = 0; j < 8; ++j) {
      float v = acc[j];
#pragma unroll
      for (int t = 0; t < 4; ++t)
        if (t < k) v += qv[t] * bf2f(rows[t][j]);
      acc[j] = v;
    }
  }

  if (lane == 0) wsLDS[wid] = l_run;
#pragma unroll
  for (int j = 0; j < 8; ++j) accLDS[wid][j * 64 + lane] = acc[j];
  __syncthreads();

  if (wid == 0) {
    const float l = wsLDS[0] + wsLDS[1] + wsLDS[2] + wsLDS[3];
    const float inv = 1.f / (l > 0.f ? l : 1.f);
    float aT[8];
#pragma unroll
    for (int j = 0; j < 8; ++j)
      aT[j] = accLDS[0][j * 64 + lane] + accLDS[1][j * 64 + lane] +
              accLDS[2][j * 64 + lane] + accLDS[3][j * 64 + lane];

    float xv[8];
    float sum = 0.f, sq = 0.f;
    {
      const u16x8 hv8 = *(const u16x8*)(resid + (size_t)n * kD + d8);
#pragma unroll
      for (int j = 0; j < 8; ++j) {
        xv[j] = bf2f(hv8[j]) + aT[j] * inv + bias[d8 + j];
        sum += xv[j];
        sq  += xv[j] * xv[j];
      }
    }
#pragma unroll
    for (int off = 32; off > 0; off >>= 1) {
      sum += __shfl_xor(sum, off);
      sq  += __shfl_xor(sq, off);
    }
    const float mean = sum * (1.f / kD);
    const float var  = sq * (1.f / kD) - mean * mean;
    const float rs = rsqrtf(var + kLnEps);
    u16x8 pk;
#pragma unroll
    for (int j = 0; j < 8; ++j) {
      const float y = fmaxf((xv[j] - mean) * rs * lng[d8 + j] + lnb[d8 + j], 0.f);
      pk[j] = f2bf(y);
    }
    *(u16x8*)(hb + (size_t)n * kD + d8) = pk;
  }
}

// ---------------------------------------------------------------------------
// Batched transpose (z<10): dst[n][k] = bf16(src[k][n]); N=512 cols each.
// z==10: concat bias build + zero counts/cursor/done (re-zeroed each replay).
// ---------------------------------------------------------------------------
struct TxJobs {
  const float* src[10];
  u16* dst[10];
  int K[10];
  const float* bl; const float* br; float* catB;
  int* counts; int* cursor; int* done;
};

__global__ __launch_bounds__(256) void transpose_all_kernel(TxJobs jobs) {
  const int z = blockIdx.z;
  if (z == 10) {
    const int lid = (blockIdx.y * 32 + blockIdx.x) * 256 + threadIdx.x;
    if (lid < 3 * 1024) {
      const int k = lid >> 10, j = lid & 1023;
      jobs.catB[lid] = (j < 512) ? jobs.bl[k * 512 + j] : jobs.br[k * 512 + j - 512];
    }
    const int cid = lid - 3 * 1024;
    if (cid >= 0 && cid < kN) jobs.counts[cid] = 0;
    const int uid = cid - kN;
    if (uid >= 0 && uid < kN) jobs.cursor[uid] = 0;
    if (uid == kN) jobs.done[0] = 0;
    return;
  }
  const int K = jobs.K[z];
  const int k0 = blockIdx.x * 32;
  if (k0 >= K) return;
  const int n0 = blockIdx.y * 32;
  const float* W = jobs.src[z];
  u16* WT = jobs.dst[z];
  __shared__ float t[32][33];
  const int lx = threadIdx.x & 31, ly = threadIdx.x >> 5;  // 32 x 8
#pragma unroll
  for (int r = 0; r < 32; r += 8)
    t[ly + r][lx] = W[(size_t)(k0 + ly + r) * 512 + n0 + lx];
  __syncthreads();
#pragma unroll
  for (int r = 0; r < 32; r += 8)
    WT[(size_t)(n0 + ly + r) * K + k0 + lx] = f2bf(t[lx][ly + r]);
}

// ------------------------- CSR build helpers -------------------------------
__global__ void count_kernel(const int* __restrict__ dst, int* __restrict__ counts) {
  const int e = blockIdx.x * 256 + threadIdx.x;
  if (e < kE) atomicAdd(&counts[dst[e]], 1);
}
// ---- fused scan: 40 blocks do local scans; the LAST block (device-scope
// atomic ticket) computes the 40-entry top scan into boff.
__global__ __launch_bounds__(256) void scan_fused_kernel(
    const int* __restrict__ counts, int* __restrict__ offsL,
    int* __restrict__ bsum, int* __restrict__ boff, int* __restrict__ done) {
  __shared__ int buf[256];
  __shared__ int lastFlag;
  const int tid = threadIdx.x, bid = blockIdx.x;
  const int i = bid * 256 + tid;
  const int v = (i < kN) ? counts[i] : 0;
  buf[tid] = v;
  __syncthreads();
  for (int off = 1; off < 256; off <<= 1) {
    const int t = (tid >= off) ? buf[tid - off] : 0;
    __syncthreads();
    buf[tid] += t;
    __syncthreads();
  }
  if (i < kN) offsL[i] = buf[tid] - v;  // block-local exclusive
  if (tid == 255) bsum[bid] = buf[255];
  __syncthreads();            // drains this block's stores (vmcnt 0)
  __threadfence();            // device-scope release
  if (tid == 0) lastFlag = (atomicAdd(done, 1) == kScanBlocks - 1);
  __syncthreads();
  if (lastFlag && tid < 64) {
    __threadfence();          // acquire side
    // forced-L2 atomic reads of every bsum entry
    const int b = (tid < kScanBlocks) ? atomicAdd(&bsum[tid], 0) : 0;
    int incl = b;
#pragma unroll
    for (int off = 1; off < 64; off <<= 1) {
      const int t = __shfl_up(incl, off);
      if (tid >= off) incl += t;
    }
    if (tid < kScanBlocks) boff[tid] = incl - b;
  }
}
// scatter metadata into dst-sorted order; slot base computed on the fly
__global__ void scatter_kernel(const int* __restrict__ dst,
                               const int* __restrict__ src,
                               const float* __restrict__ ea,
                               const int* __restrict__ offsL,
                               const int* __restrict__ boff,
                               int* __restrict__ cursor,
                               int* __restrict__ esrcS,
                               float2* __restrict__ eaS) {
  const int e = blockIdx.x * 256 + threadIdx.x;
  if (e >= kE) return;
  const int d = dst[e];
  const int p = offsL[d] + boff[d >> 8] + atomicAdd(&cursor[d], 1);
  esrcS[p] = src[e];
  eaS[p] = *(const float2*)(ea + (size_t)e * 2);
}

}  // namespace

extern "C" void kernel_launch(void* const* d_in, const int* in_sizes, int n_in,
                              void* d_out, int out_size, void* d_ws, size_t ws_size,
                              hipStream_t stream) {
  const float* x         = (const float*)d_in[0];
  const float* edge_attr = (const float*)d_in[1];
  const float* emb_inv_W = (const float*)d_in[2];
  const float* emb_inv_b = (const float*)d_in[3];
  const float* emb_org_W = (const float*)d_in[4];
  const float* emb_org_b = (const float*)d_in[5];
  const float* gat_Wl    = (const float*)d_in[6];
  const float* gat_bl    = (const float*)d_in[7];
  const float* gat_Wr    = (const float*)d_in[8];
  const float* gat_br    = (const float*)d_in[9];
  const float* gat_We    = (const float*)d_in[10];
  const float* gat_att   = (const float*)d_in[11];
  const float* gat_bias  = (const float*)d_in[12];
  const float* ln_g      = (const float*)d_in[13];
  const float* ln_b      = (const float*)d_in[14];
  const float* lin0_W    = (const float*)d_in[15];
  const float* lin0_b    = (const float*)d_in[16];
  const float* lin1_W    = (const float*)d_in[17];
  const float* lin1_b    = (const float*)d_in[18];
  const int*   edge_idx  = (const int*)d_in[19];
  const int* src = edge_idx;
  const int* dst = edge_idx + kE;
  float* out = (float*)d_out;

  // ---- workspace layout (~58 MB) ----
  float* catB = (float*)d_ws;          // [3,1024] concat gat biases
  u16* hb0  = (u16*)(catB + 3072);     // [N,D] bf16 initial embedding (residual 0)
  u16* hb   = hb0 + kND;               // [N,D] bf16 running h (residual stream)
  u16* xlB  = hb + kND;                // [N,D]
  u16* xrB  = xlB + kND;               // [N,D]
  u16* y0b  = xrB + kND;               // [4000,512]
  u16* y1b  = y0b + kNinv * kD;        // [3000,512]
  u16* embInvT = y1b + kNunk * kD;     // [512,512]
  u16* embOrgT = embInvT + 262144;
  u16* WlrT    = embOrgT + 262144;     // 3 x [1024,512] (WlT rows 0-511, WrT 512-1023)
  u16* lin0T   = WlrT + 3 * 524288;    // [512,1024]
  u16* lin1T   = lin0T + 524288;
  int* counts  = (int*)(lin1T + 524288);  // [N]
  int* offsL   = counts + kN;             // [N] block-local exclusive scan
  int* cursor  = offsL + kN;              // [N]
  int* bsum    = cursor + kN;             // [kScanBlocks]
  int* boff    = bsum + kScanBlocks;      // [kScanBlocks]
  int* done    = boff + kScanBlocks;      // [1]
  int* esrcS   = done + 1;                // [E] src in dst-sorted order
  float2* eaS  = (float2*)(esrcS + kE);   // [E] edge_attr in dst-sorted order

  const dim3 blk(256);
  auto cdiv = [](int a, int b) { return (a + b - 1) / b; };
  Job2 jNone{};
  jNone.xSplit = 0x7FFFFFFF;

  // ---- 0. setup: batched weight transpose + (z=10) catbias + zeroing
  {
    TxJobs j;
    j.src[0] = emb_inv_W;  j.dst[0] = embInvT;  j.K[0] = 512;
    j.src[1] = emb_org_W;  j.dst[1] = embOrgT;  j.K[1] = 512;
    for (int k = 0; k < 3; ++k) {
      j.src[2 + k] = gat_Wl + (size_t)k * kD * kD;
      j.dst[2 + k] = WlrT + (size_t)k * 524288;            // rows 0..511
      j.K[2 + k] = 512;
      j.src[5 + k] = gat_Wr + (size_t)k * kD * kD;
      j.dst[5 + k] = WlrT + (size_t)k * 524288 + 262144;   // rows 512..1023
      j.K[5 + k] = 512;
    }
    j.src[8] = lin0_W; j.dst[8] = lin0T; j.K[8] = 1024;
    j.src[9] = lin1_W; j.dst[9] = lin1T; j.K[9] = 1024;
    j.bl = gat_bl; j.br = gat_br; j.catB = catB;
    j.counts = counts; j.cursor = cursor; j.done = done;
    transpose_all_kernel<<<dim3(32, 16, 11), blk, 0, stream>>>(j);
  }

  // ---- 1. embeddings (merged pair; A = fp32 x reg-staged) -> hb0
  {
    Job2 je;
    je.A1 = (const u16*)(x + (size_t)kNinv * kD);
    je.A2 = nullptr;
    je.BT = embOrgT;
    je.bias = emb_org_b;
    je.Cb = hb0 + (size_t)kNinv * kD;
    je.M = kN - kNinv;
    je.xSplit = cdiv(kNinv, 128);  // 32
    const int gx = je.xSplit + cdiv(kN - kNinv, 128);  // 32 + 47
    gemm_bf16<false, true, true><<<dim3(gx, 4), blk, 0, stream>>>(
        (const u16*)x, nullptr, embInvT, emb_inv_b, nullptr, hb0, nullptr, 0,
        kNinv, kD, kD, kD, je);
  }

  // ---- 2. CSR: count -> fused scan (last-block top) -> scatter  (3 dispatches)
  count_kernel<<<dim3(cdiv(kE, 256)), blk, 0, stream>>>(dst, counts);
  scan_fused_kernel<<<dim3(kScanBlocks), blk, 0, stream>>>(counts, offsL, bsum,
                                                           boff, done);
  scatter_kernel<<<dim3(cdiv(kE, 256)), blk, 0, stream>>>(dst, src, edge_attr,
                                                          offsL, boff, cursor,
                                                          esrcS, eaS);

  // ---- 3. GAT layers: 1 fused lr-GEMM + 1 fused attention kernel each
  for (int k = 0; k < 3; ++k) {
    const u16* hIn = (k == 0) ? hb0 : hb;
    gemm_bf16<false, true, false><<<dim3(cdiv(kN, 128), 8), blk, 0, stream>>>(
        hIn, nullptr, WlrT + (size_t)k * 524288, catB + k * 1024,
        nullptr, xlB, xrB, 512, kN, 1024, kD, kD, jNone);
    gat_fused_kernel<<<dim3(kN), blk, 0, stream>>>(
        xlB, xrB, esrcS, eaS, offsL, boff,
        gat_We + (size_t)k * 2 * kD, gat_att + (size_t)k * kD,
        gat_bias + (size_t)k * kD, ln_g + (size_t)k * kD,
        ln_b + (size_t)k * kD, hIn, hb);
  }

  // ---- 4. heads (merged pair) via A-split ([hb0 | hb] along K): y0, y1
  {
    const size_t off = (size_t)(kN - kNunk) * kD;
    Job2 jh;
    jh.A1 = hb0 + off;
    jh.A2 = hb + off;
    jh.BT = lin1T;
    jh.bias = lin1_b;
    jh.Cb = y1b;
    jh.M = kNunk;
    jh.xSplit = cdiv(kNinv, 128);  // 32
    const int gx = jh.xSplit + cdiv(kNunk, 128);  // 32 + 24
    gemm_bf16<false, true, false><<<dim3(gx, 4), blk, 0, stream>>>(
        hb0, hb, lin0T, lin0_b, nullptr, y0b, nullptr, 0,
        kNinv, kD, 2 * kD, kD, jh);
  }

  // ---- 5. out = y0 @ y1^T  [4000,3000]
  gemm_bf16<true, false, false><<<dim3(cdiv(kNinv, 128), cdiv(kNunk, 128)), blk, 0,
                                  stream>>>(
      y0b, nullptr, y1b, nullptr, out, nullptr, nullptr, 0,
      kNinv, kNunk, kD, kNunk, jNone);
}

// Round 21
// 359.964 us; speedup vs baseline: 1.3625x; 1.0083x over previous
//
#include <hip/hip_runtime.h>
#include <cstddef>
#include <cstdint>

namespace {

using u16 = unsigned short;
typedef __attribute__((ext_vector_type(8))) unsigned short u16x8;
typedef __attribute__((ext_vector_type(8))) short bf16x8;
typedef __attribute__((ext_vector_type(4))) float f32x4;

constexpr int kN    = 10000;   // nodes
constexpr int kE    = 160000;  // edges
constexpr int kD    = 512;     // feature dim
constexpr int kNinv = 4000;
constexpr int kNunk = 3000;
constexpr int kND   = kN * kD;
constexpr int kScanBlocks = (kN + 255) / 256;  // 40
constexpr float kLnEps = 1e-5f;

__device__ __forceinline__ float bf2f(u16 u) {
  return __uint_as_float((unsigned)u << 16);
}
__device__ __forceinline__ u16 f2bf(float f) {
  unsigned u = __float_as_uint(f);
  return (u16)((u + 0x7FFFu + ((u >> 16) & 1u)) >> 16);  // RNE
}

__device__ __forceinline__ void gload_lds16(const void* g, void* l) {
  __builtin_amdgcn_global_load_lds(
      (const __attribute__((address_space(1))) void*)(unsigned long long)(uintptr_t)g,
      (__attribute__((address_space(3))) void*)(unsigned)(uintptr_t)l,
      16, 0, 0);
}

// second job for merged dual-GEMM dispatches; xSplit = #x-blocks of job 0
struct Job2 {
  const u16* A1; const u16* A2; const u16* BT; const float* bias;
  u16* Cb; int M; int xSplit;
};

// ---------------------------------------------------------------------------
// bf16 MFMA GEMM: C[M,N] = A[M,K] * BT[N,K]^T (+ bias)
// (R11: operand-swap packed epilogue + XCD-bijective swizzle)
// A_F32: A fp32, reg-staged (2xfloat4 -> RNE bf16 -> same swizzled LDS slot).
// Job2: blocks with bx >= xSplit run the second job.
// ---------------------------------------------------------------------------
template <bool WRITE_F32, bool WRITE_BF16, bool A_F32>
__global__ __launch_bounds__(256) void gemm_bf16(
    const u16* __restrict__ A1, const u16* __restrict__ A2,
    const u16* __restrict__ BT, const float* __restrict__ bias,
    float* __restrict__ Cf, u16* __restrict__ Cb, u16* __restrict__ Cb2,
    int nsplit, int M, int N, int K, int ldc, Job2 j2) {
  __shared__ u16 As[128 * 64];  // 16 KB
  __shared__ u16 Bs[128 * 64];  // 16 KB
  const int tid  = threadIdx.x;
  const int lane = tid & 63;
  const int wid  = tid >> 6;

  // ---- XCD-bijective swizzle over the linear block id (m204)
  const int nwg = gridDim.x * gridDim.y;
  int wg = blockIdx.x + gridDim.x * blockIdx.y;
  {
    const int xcd = wg & 7, idx = wg >> 3;
    const int q = nwg >> 3, r = nwg & 7;
    wg = (xcd < r ? xcd * (q + 1) : r * (q + 1) + (xcd - r) * q) + idx;
  }
  int bx = wg % gridDim.x;
  const int ny = wg / gridDim.x;

  // ---- job select
  const u16* jA1 = A1; const u16* jA2 = A2; const u16* jBT = BT;
  const float* jbias = bias; u16* jCb = Cb; int jM = M;
  if (bx >= j2.xSplit) {
    bx -= j2.xSplit;
    jA1 = j2.A1; jA2 = j2.A2; jBT = j2.BT;
    jbias = j2.bias; jCb = j2.Cb; jM = j2.M;
  }
  const int bm = bx * 128;
  const int bn = ny * 128;

  const int wr = (wid >> 1) * 64;
  const int wc = (wid & 1) * 64;

  f32x4 acc[4][4];
#pragma unroll
  for (int m = 0; m < 4; ++m)
#pragma unroll
    for (int n = 0; n < 4; ++n) acc[m][n] = (f32x4){0.f, 0.f, 0.f, 0.f};

  const int srow = lane >> 3;  // 0..7
  const int slot = lane & 7;   // 16B slot in 128B row
  const size_t astride = (jA2 != nullptr) ? 512 : (size_t)K;

  for (int k0 = 0; k0 < K; k0 += 64) {
    const u16* Ap = jA1;
    int kof = k0;
    if (jA2 != nullptr && k0 >= 512) { Ap = jA2; kof = k0 - 512; }
#pragma unroll
    for (int t = 0; t < 4; ++t) {
      const int inst = wid * 4 + t;
      const int row  = inst * 8 + srow;
      const int scol = ((slot ^ (row & 7)) << 4);    // byte offset in bf16 row
      const int ar   = min(bm + row, jM - 1);
      if constexpr (A_F32) {
        const float* srcf = (const float*)Ap + (size_t)ar * astride + kof + (scol >> 1);
        const float4 v0 = *reinterpret_cast<const float4*>(srcf);
        const float4 v1 = *reinterpret_cast<const float4*>(srcf + 4);
        u16x8 pk;
        pk[0] = f2bf(v0.x); pk[1] = f2bf(v0.y); pk[2] = f2bf(v0.z); pk[3] = f2bf(v0.w);
        pk[4] = f2bf(v1.x); pk[5] = f2bf(v1.y); pk[6] = f2bf(v1.z); pk[7] = f2bf(v1.w);
        *reinterpret_cast<u16x8*>((char*)As + inst * 1024 + lane * 16) = pk;
      } else {
        gload_lds16((const char*)Ap + ((size_t)ar * astride + kof) * 2 + scol,
                    (char*)As + inst * 1024);
      }
    }
#pragma unroll
    for (int t = 0; t < 4; ++t) {
      const int inst = wid * 4 + t;
      const int row  = inst * 8 + srow;
      const int scol = ((slot ^ (row & 7)) << 4);
      const int bc   = min(bn + row, N - 1);
      gload_lds16((const char*)jBT + ((size_t)bc * K + k0) * 2 + scol,
                  (char*)Bs + inst * 1024);
    }
    asm volatile("s_waitcnt vmcnt(0)" ::: "memory");
    __syncthreads();

#pragma unroll
    for (int kk = 0; kk < 2; ++kk) {
      bf16x8 af[4], bfr[4];
#pragma unroll
      for (int m = 0; m < 4; ++m) {
        const int r = wr + m * 16 + (lane & 15);
        const int s = kk * 4 + (lane >> 4);
        af[m] = *(const bf16x8*)((const char*)As + r * 128 + ((s ^ (r & 7)) << 4));
      }
#pragma unroll
      for (int n = 0; n < 4; ++n) {
        const int c = wc + n * 16 + (lane & 15);
        const int s = kk * 4 + (lane >> 4);
        bfr[n] = *(const bf16x8*)((const char*)Bs + c * 128 + ((s ^ (c & 7)) << 4));
      }
      // operand-swapped: accumulates the C^T fragment (same sums, new layout)
#pragma unroll
      for (int m = 0; m < 4; ++m)
#pragma unroll
        for (int n = 0; n < 4; ++n)
          acc[m][n] = __builtin_amdgcn_mfma_f32_16x16x32_bf16(bfr[n], af[m],
                                                              acc[m][n], 0, 0, 0);
    }
    __syncthreads();
  }

  // ---- epilogue: thread holds C[r, c0..c0+3]
#pragma unroll
  for (int m = 0; m < 4; ++m) {
    const int r = bm + wr + m * 16 + (lane & 15);
    if (r >= jM) continue;
#pragma unroll
    for (int n = 0; n < 4; ++n) {
      const int c0 = bn + wc + n * 16 + ((lane >> 4) << 2);
      if (c0 >= N) continue;  // N%4==0 -> whole 4-pack in range
      float4 bv = make_float4(0.f, 0.f, 0.f, 0.f);
      if (jbias != nullptr) bv = *reinterpret_cast<const float4*>(jbias + c0);
      float v0 = acc[m][n][0] + bv.x;
      float v1 = acc[m][n][1] + bv.y;
      float v2 = acc[m][n][2] + bv.z;
      float v3 = acc[m][n][3] + bv.w;
      if (WRITE_F32) {
        float4 o; o.x = v0; o.y = v1; o.z = v2; o.w = v3;
        *reinterpret_cast<float4*>(Cf + (size_t)r * ldc + c0) = o;
      }
      if (WRITE_BF16) {
        u16* dstp = jCb;
        int c = c0;
        if (Cb2 != nullptr && c0 >= nsplit) { dstp = Cb2; c = c0 - nsplit; }
        ushort4 o;
        o.x = f2bf(v0); o.y = f2bf(v1); o.z = f2bf(v2); o.w = f2bf(v3);
        *reinterpret_cast<ushort4*>(dstp + (size_t)r * ldc + c) = o;
      }
    }
  }
}

// ---------------------------------------------------------------------------
// Fused per-node GATv2 attention + residual + LayerNorm + ReLU.
// (R15/R17/R18 kernel verbatim — best measured: 65.5 us; materialized offs.)
// ---------------------------------------------------------------------------
__global__ __launch_bounds__(256) void gat_fused_kernel(
    const u16* __restrict__ xl, const u16* __restrict__ xr,
    const int* __restrict__ esrcS, const float2* __restrict__ eaS,
    const int* __restrict__ offs, const float* __restrict__ We,
    const float* __restrict__ att, const float* __restrict__ bias,
    const float* __restrict__ lng, const float* __restrict__ lnb,
    const u16* __restrict__ resid, u16* __restrict__ hb) {
  __shared__ float accLDS[4][512];
  __shared__ float wsLDS[4];
  const int wid = threadIdx.x >> 6, lane = threadIdx.x & 63;
  const int n = blockIdx.x;
  const int d8 = lane * 8;

  float r8[8], w0[8], w1[8], a06[8], a04[8];
  {
    const u16x8 rv = *(const u16x8*)(xr + (size_t)n * kD + d8);
#pragma unroll
    for (int i = 0; i < 8; ++i) {
      r8[i] = bf2f(rv[i]);
      w0[i] = We[d8 + i];
      w1[i] = We[kD + d8 + i];
      const float a = att[d8 + i];
      a06[i] = 0.6f * a;      // lrelu(m) = 0.6m + 0.4|m| for slope 0.2
      a04[i] = 0.4f * a;
    }
  }

  float acc[8];
#pragma unroll
  for (int j = 0; j < 8; ++j) acc[j] = 0.f;
  float l_run = 0.f;

  const int beg = offs[n], end = offs[n + 1];
  const int cnt = end - beg;
  const int q = cnt >> 2, r = cnt & 3;
  const int myCnt = q + ((wid < r) ? 1 : 0);
  const int myBeg = beg + wid * q + min(wid, r);

  int sv = 0;
  float2 e2 = make_float2(0.f, 0.f);
  if (lane < myCnt) {
    sv = esrcS[myBeg + lane];
    e2 = eaS[myBeg + lane];
  }

  for (int i = 0; i < myCnt; i += 4) {
    const int k = myCnt - i;  // wave-uniform guards
    u16x8 rows[4];
#pragma unroll
    for (int t = 0; t < 4; ++t)
      if (t < k)
        rows[t] = *(const u16x8*)(xl + (size_t)__shfl(sv, i + t) * kD + d8);
    float s[4];
#pragma unroll
    for (int t = 0; t < 4; ++t) {
      s[t] = 0.f;
      if (t < k) {
        const float ex = __shfl(e2.x, i + t), ey = __shfl(e2.y, i + t);
#pragma unroll
        for (int j = 0; j < 8; ++j) {
          const float m = bf2f(rows[t][j]) + r8[j] + ex * w0[j] + ey * w1[j];
          s[t] += a06[j] * m + a04[j] * fabsf(m);
        }
      }
    }
#pragma unroll
    for (int off = 32; off > 0; off >>= 1)
#pragma unroll
      for (int t = 0; t < 4; ++t)
        if (t < k) s[t] += __shfl_xor(s[t], off);
    float qv[4];
    float ws = 0.f;
#pragma unroll
    for (int t = 0; t < 4; ++t) {
      qv[t] = (t < k) ? __expf(s[t]) : 0.f;
      ws += qv[t];
    }
    l_run += ws;
#pragma unroll
    for (int j = 0; j < 8; ++j) {
      float v = acc[j];
#pragma unroll
      for (int t = 0; t < 4; ++t)
        if (t < k) v += qv[t] * bf2f(rows[t][j]);
      acc[j] = v;
    }
  }

  if (lane == 0) wsLDS[wid] = l_run;
#pragma unroll
  for (int j = 0; j < 8; ++j) accLDS[wid][j * 64 + lane] = acc[j];
  __syncthreads();

  if (wid == 0) {
    const float l = wsLDS[0] + wsLDS[1] + wsLDS[2] + wsLDS[3];
    const float inv = 1.f / (l > 0.f ? l : 1.f);
    float aT[8];
#pragma unroll
    for (int j = 0; j < 8; ++j)
      aT[j] = accLDS[0][j * 64 + lane] + accLDS[1][j * 64 + lane] +
              accLDS[2][j * 64 + lane] + accLDS[3][j * 64 + lane];

    float xv[8];
    float sum = 0.f, sq = 0.f;
    {
      const u16x8 hv8 = *(const u16x8*)(resid + (size_t)n * kD + d8);
#pragma unroll
      for (int j = 0; j < 8; ++j) {
        xv[j] = bf2f(hv8[j]) + aT[j] * inv + bias[d8 + j];
        sum += xv[j];
        sq  += xv[j] * xv[j];
      }
    }
#pragma unroll
    for (int off = 32; off > 0; off >>= 1) {
      sum += __shfl_xor(sum, off);
      sq  += __shfl_xor(sq, off);
    }
    const float mean = sum * (1.f / kD);
    const float var  = sq * (1.f / kD) - mean * mean;
    const float rs = rsqrtf(var + kLnEps);
    u16x8 pk;
#pragma unroll
    for (int j = 0; j < 8; ++j) {
      const float y = fmaxf((xv[j] - mean) * rs * lng[d8 + j] + lnb[d8 + j], 0.f);
      pk[j] = f2bf(y);
    }
    *(u16x8*)(hb + (size_t)n * kD + d8) = pk;
  }
}

// ---------------------------------------------------------------------------
// Batched transpose (z<10): dst[n][k] = bf16(src[k][n]); N=512 cols each.
// z==10: concat bias build + zero counts/done (re-zeroed each replay).
// ---------------------------------------------------------------------------
struct TxJobs {
  const float* src[10];
  u16* dst[10];
  int K[10];
  const float* bl; const float* br; float* catB;
  int* counts; int* done;
};

__global__ __launch_bounds__(256) void transpose_all_kernel(TxJobs jobs) {
  const int z = blockIdx.z;
  if (z == 10) {
    const int lid = (blockIdx.y * 32 + blockIdx.x) * 256 + threadIdx.x;
    if (lid < 3 * 1024) {
      const int k = lid >> 10, j = lid & 1023;
      jobs.catB[lid] = (j < 512) ? jobs.bl[k * 512 + j] : jobs.br[k * 512 + j - 512];
    }
    const int cid = lid - 3 * 1024;
    if (cid >= 0 && cid < kN) jobs.counts[cid] = 0;
    if (cid == kN) jobs.done[0] = 0;
    return;
  }
  const int K = jobs.K[z];
  const int k0 = blockIdx.x * 32;
  if (k0 >= K) return;
  const int n0 = blockIdx.y * 32;
  const float* W = jobs.src[z];
  u16* WT = jobs.dst[z];
  __shared__ float t[32][33];
  const int lx = threadIdx.x & 31, ly = threadIdx.x >> 5;  // 32 x 8
#pragma unroll
  for (int r = 0; r < 32; r += 8)
    t[ly + r][lx] = W[(size_t)(k0 + ly + r) * 512 + n0 + lx];
  __syncthreads();
#pragma unroll
  for (int r = 0; r < 32; r += 8)
    WT[(size_t)(n0 + ly + r) * K + k0 + lx] = f2bf(t[lx][ly + r]);
}

// ------------------------- CSR build helpers -------------------------------
__global__ void count_kernel(const int* __restrict__ dst, int* __restrict__ counts) {
  const int e = blockIdx.x * 256 + threadIdx.x;
  if (e < kE) atomicAdd(&counts[dst[e]], 1);
}
// ---- fused scan: 40 blocks do local scans; the LAST block (device-scope
// atomic ticket) computes the 40-entry top scan into boff. (Validated R20.)
__global__ __launch_bounds__(256) void scan_fused_kernel(
    const int* __restrict__ counts, int* __restrict__ offsL,
    int* __restrict__ bsum, int* __restrict__ boff, int* __restrict__ done) {
  __shared__ int buf[256];
  __shared__ int lastFlag;
  const int tid = threadIdx.x, bid = blockIdx.x;
  const int i = bid * 256 + tid;
  const int v = (i < kN) ? counts[i] : 0;
  buf[tid] = v;
  __syncthreads();
  for (int off = 1; off < 256; off <<= 1) {
    const int t = (tid >= off) ? buf[tid - off] : 0;
    __syncthreads();
    buf[tid] += t;
    __syncthreads();
  }
  if (i < kN) offsL[i] = buf[tid] - v;  // block-local exclusive
  if (tid == 255) bsum[bid] = buf[255];
  __syncthreads();
  __threadfence();            // device-scope release
  if (tid == 0) lastFlag = (atomicAdd(done, 1) == kScanBlocks - 1);
  __syncthreads();
  if (lastFlag && tid < 64) {
    __threadfence();          // acquire side
    const int b = (tid < kScanBlocks) ? atomicAdd(&bsum[tid], 0) : 0;
    int incl = b;
#pragma unroll
    for (int off = 1; off < 64; off <<= 1) {
      const int t = __shfl_up(incl, off);
      if (tid >= off) incl += t;
    }
    if (tid < kScanBlocks) boff[tid] = incl - b;
  }
}
// materialize offs/pos (gat + scatter use them directly; offs[kN] = kE)
__global__ __launch_bounds__(256) void scan_add_kernel(
    const int* __restrict__ offsL, const int* __restrict__ boff,
    int* __restrict__ offs, int* __restrict__ pos) {
  const int i = blockIdx.x * 256 + threadIdx.x;
  if (i < kN) {
    const int o = offsL[i] + boff[i >> 8];
    offs[i] = o;
    pos[i] = o;
  }
  if (i == 0) offs[kN] = kE;
}
// scatter metadata into dst-sorted order
__global__ void scatter_kernel(const int* __restrict__ dst,
                               const int* __restrict__ src,
                               const float* __restrict__ ea,
                               int* __restrict__ pos,
                               int* __restrict__ esrcS,
                               float2* __restrict__ eaS) {
  const int e = blockIdx.x * 256 + threadIdx.x;
  if (e >= kE) return;
  const int p = atomicAdd(&pos[dst[e]], 1);
  esrcS[p] = src[e];
  eaS[p] = *(const float2*)(ea + (size_t)e * 2);
}

}  // namespace

extern "C" void kernel_launch(void* const* d_in, const int* in_sizes, int n_in,
                              void* d_out, int out_size, void* d_ws, size_t ws_size,
                              hipStream_t stream) {
  const float* x         = (const float*)d_in[0];
  const float* edge_attr = (const float*)d_in[1];
  const float* emb_inv_W = (const float*)d_in[2];
  const float* emb_inv_b = (const float*)d_in[3];
  const float* emb_org_W = (const float*)d_in[4];
  const float* emb_org_b = (const float*)d_in[5];
  const float* gat_Wl    = (const float*)d_in[6];
  const float* gat_bl    = (const float*)d_in[7];
  const float* gat_Wr    = (const float*)d_in[8];
  const float* gat_br    = (const float*)d_in[9];
  const float* gat_We    = (const float*)d_in[10];
  const float* gat_att   = (const float*)d_in[11];
  const float* gat_bias  = (const float*)d_in[12];
  const float* ln_g      = (const float*)d_in[13];
  const float* ln_b      = (const float*)d_in[14];
  const float* lin0_W    = (const float*)d_in[15];
  const float* lin0_b    = (const float*)d_in[16];
  const float* lin1_W    = (const float*)d_in[17];
  const float* lin1_b    = (const float*)d_in[18];
  const int*   edge_idx  = (const int*)d_in[19];
  const int* src = edge_idx;
  const int* dst = edge_idx + kE;
  float* out = (float*)d_out;

  // ---- workspace layout (~58 MB) ----
  float* catB = (float*)d_ws;          // [3,1024] concat gat biases
  u16* hb0  = (u16*)(catB + 3072);     // [N,D] bf16 initial embedding (residual 0)
  u16* hb   = hb0 + kND;               // [N,D] bf16 running h (residual stream)
  u16* xlB  = hb + kND;                // [N,D]
  u16* xrB  = xlB + kND;               // [N,D]
  u16* y0b  = xrB + kND;               // [4000,512]
  u16* y1b  = y0b + kNinv * kD;        // [3000,512]
  u16* embInvT = y1b + kNunk * kD;     // [512,512]
  u16* embOrgT = embInvT + 262144;
  u16* WlrT    = embOrgT + 262144;     // 3 x [1024,512] (WlT rows 0-511, WrT 512-1023)
  u16* lin0T   = WlrT + 3 * 524288;    // [512,1024]
  u16* lin1T   = lin0T + 524288;
  int* counts  = (int*)(lin1T + 524288);  // [N]
  int* offsL   = counts + kN;             // [N] block-local exclusive scan
  int* offs    = offsL + kN;              // [N+1]
  int* pos     = offs + kN + 1;           // [N]
  int* bsum    = pos + kN;                // [kScanBlocks]
  int* boff    = bsum + kScanBlocks;      // [kScanBlocks]
  int* done    = boff + kScanBlocks;      // [1]
  int* esrcS   = done + 1;                // [E] src in dst-sorted order
  float2* eaS  = (float2*)(esrcS + kE);   // [E] edge_attr in dst-sorted order

  const dim3 blk(256);
  auto cdiv = [](int a, int b) { return (a + b - 1) / b; };
  Job2 jNone{};
  jNone.xSplit = 0x7FFFFFFF;

  // ---- 0. setup: batched weight transpose + (z=10) catbias + zeroing
  {
    TxJobs j;
    j.src[0] = emb_inv_W;  j.dst[0] = embInvT;  j.K[0] = 512;
    j.src[1] = emb_org_W;  j.dst[1] = embOrgT;  j.K[1] = 512;
    for (int k = 0; k < 3; ++k) {
      j.src[2 + k] = gat_Wl + (size_t)k * kD * kD;
      j.dst[2 + k] = WlrT + (size_t)k * 524288;            // rows 0..511
      j.K[2 + k] = 512;
      j.src[5 + k] = gat_Wr + (size_t)k * kD * kD;
      j.dst[5 + k] = WlrT + (size_t)k * 524288 + 262144;   // rows 512..1023
      j.K[5 + k] = 512;
    }
    j.src[8] = lin0_W; j.dst[8] = lin0T; j.K[8] = 1024;
    j.src[9] = lin1_W; j.dst[9] = lin1T; j.K[9] = 1024;
    j.bl = gat_bl; j.br = gat_br; j.catB = catB;
    j.counts = counts; j.done = done;
    transpose_all_kernel<<<dim3(32, 16, 11), blk, 0, stream>>>(j);
  }

  // ---- 1. embeddings (merged pair; A = fp32 x reg-staged) -> hb0
  {
    Job2 je;
    je.A1 = (const u16*)(x + (size_t)kNinv * kD);
    je.A2 = nullptr;
    je.BT = embOrgT;
    je.bias = emb_org_b;
    je.Cb = hb0 + (size_t)kNinv * kD;
    je.M = kN - kNinv;
    je.xSplit = cdiv(kNinv, 128);  // 32
    const int gx = je.xSplit + cdiv(kN - kNinv, 128);  // 32 + 47
    gemm_bf16<false, true, true><<<dim3(gx, 4), blk, 0, stream>>>(
        (const u16*)x, nullptr, embInvT, emb_inv_b, nullptr, hb0, nullptr, 0,
        kNinv, kD, kD, kD, je);
  }

  // ---- 2. CSR: count -> fused scan -> materialize -> scatter (4 dispatches)
  count_kernel<<<dim3(cdiv(kE, 256)), blk, 0, stream>>>(dst, counts);
  scan_fused_kernel<<<dim3(kScanBlocks), blk, 0, stream>>>(counts, offsL, bsum,
                                                           boff, done);
  scan_add_kernel<<<dim3(kScanBlocks), blk, 0, stream>>>(offsL, boff, offs, pos);
  scatter_kernel<<<dim3(cdiv(kE, 256)), blk, 0, stream>>>(dst, src, edge_attr, pos,
                                                          esrcS, eaS);

  // ---- 3. GAT layers: 1 fused lr-GEMM + 1 fused attention kernel each
  for (int k = 0; k < 3; ++k) {
    const u16* hIn = (k == 0) ? hb0 : hb;
    gemm_bf16<false, true, false><<<dim3(cdiv(kN, 128), 8), blk, 0, stream>>>(
        hIn, nullptr, WlrT + (size_t)k * 524288, catB + k * 1024,
        nullptr, xlB, xrB, 512, kN, 1024, kD, kD, jNone);
    gat_fused_kernel<<<dim3(kN), blk, 0, stream>>>(
        xlB, xrB, esrcS, eaS, offs,
        gat_We + (size_t)k * 2 * kD, gat_att + (size_t)k * kD,
        gat_bias + (size_t)k * kD, ln_g + (size_t)k * kD,
        ln_b + (size_t)k * kD, hIn, hb);
  }

  // ---- 4. heads (merged pair) via A-split ([hb0 | hb] along K): y0, y1
  {
    const size_t off = (size_t)(kN - kNunk) * kD;
    Job2 jh;
    jh.A1 = hb0 + off;
    jh.A2 = hb + off;
    jh.BT = lin1T;
    jh.bias = lin1_b;
    jh.Cb = y1b;
    jh.M = kNunk;
    jh.xSplit = cdiv(kNinv, 128);  // 32
    const int gx = jh.xSplit + cdiv(kNunk, 128);  // 32 + 24
    gemm_bf16<false, true, false><<<dim3(gx, 4), blk, 0, stream>>>(
        hb0, hb, lin0T, lin0_b, nullptr, y0b, nullptr, 0,
        kNinv, kD, 2 * kD, kD, jh);
  }

  // ---- 5. out = y0 @ y1^T  [4000,3000]
  gemm_bf16<true, false, false><<<dim3(cdiv(kNinv, 128), cdiv(kNunk, 128)), blk, 0,
                                  stream>>>(
      y0b, nullptr, y1b, nullptr, out, nullptr, nullptr, 0,
      kNinv, kNunk, kD, kNunk, jNone);
}

// Round 22
// 358.290 us; speedup vs baseline: 1.3689x; 1.0047x over previous
//
#include <hip/hip_runtime.h>
#include <cstddef>
#include <cstdint>

namespace {

using u16 = unsigned short;
typedef __attribute__((ext_vector_type(8))) unsigned short u16x8;
typedef __attribute__((ext_vector_type(8))) short bf16x8;
typedef __attribute__((ext_vector_type(4))) float f32x4;

constexpr int kN    = 10000;   // nodes
constexpr int kE    = 160000;  // edges
constexpr int kD    = 512;     // feature dim
constexpr int kNinv = 4000;
constexpr int kNunk = 3000;
constexpr int kND   = kN * kD;
constexpr int kScanBlocks = (kN + 255) / 256;  // 40
constexpr float kLnEps = 1e-5f;

__device__ __forceinline__ float bf2f(u16 u) {
  return __uint_as_float((unsigned)u << 16);
}
__device__ __forceinline__ u16 f2bf(float f) {
  unsigned u = __float_as_uint(f);
  return (u16)((u + 0x7FFFu + ((u >> 16) & 1u)) >> 16);  // RNE
}

__device__ __forceinline__ void gload_lds16(const void* g, void* l) {
  __builtin_amdgcn_global_load_lds(
      (const __attribute__((address_space(1))) void*)(unsigned long long)(uintptr_t)g,
      (__attribute__((address_space(3))) void*)(unsigned)(uintptr_t)l,
      16, 0, 0);
}

// second job for merged dual-GEMM dispatches; xSplit = #x-blocks of job 0
struct Job2 {
  const u16* A1; const u16* A2; const u16* BT; const float* bias;
  u16* Cb; int M; int xSplit;
};

// piggyback work carried on the last grid row of a GEMM dispatch
// mode 0: none; 1: edge count; 2: edge scatter
struct Extra {
  int mode;
  const int* dst; const int* src; const float* ea;
  int* counts; int* pos; int* esrcS; float2* eaS;
};

// ---------------------------------------------------------------------------
// bf16 MFMA GEMM: C[M,N] = A[M,K] * BT[N,K]^T (+ bias)
// (R11: operand-swap packed epilogue + XCD-bijective swizzle)
// A_F32: A fp32, reg-staged. Job2: second GEMM job for bx >= xSplit.
// Extra: blocks on the last grid row do edge count/scatter instead of GEMM.
// ---------------------------------------------------------------------------
template <bool WRITE_F32, bool WRITE_BF16, bool A_F32>
__global__ __launch_bounds__(256) void gemm_bf16(
    const u16* __restrict__ A1, const u16* __restrict__ A2,
    const u16* __restrict__ BT, const float* __restrict__ bias,
    float* __restrict__ Cf, u16* __restrict__ Cb, u16* __restrict__ Cb2,
    int nsplit, int M, int N, int K, int ldc, Job2 j2, Extra ex) {
  __shared__ u16 As[128 * 64];  // 16 KB
  __shared__ u16 Bs[128 * 64];  // 16 KB
  const int tid  = threadIdx.x;
  const int lane = tid & 63;
  const int wid  = tid >> 6;

  // ---- XCD-bijective swizzle over the linear block id (m204)
  const int nwg = gridDim.x * gridDim.y;
  int wg = blockIdx.x + gridDim.x * blockIdx.y;
  {
    const int xcd = wg & 7, idx = wg >> 3;
    const int q = nwg >> 3, r = nwg & 7;
    wg = (xcd < r ? xcd * (q + 1) : r * (q + 1) + (xcd - r) * q) + idx;
  }
  int bx = wg % gridDim.x;
  const int ny = wg / gridDim.x;

  // ---- piggyback slice (last grid row)
  if (ex.mode != 0 && ny == (int)gridDim.y - 1) {
    const int base = bx * 256 + tid;
    const int stride = gridDim.x * 256;
    if (ex.mode == 1) {
      for (int e = base; e < kE; e += stride) atomicAdd(&ex.counts[ex.dst[e]], 1);
    } else {
      for (int e = base; e < kE; e += stride) {
        const int p = atomicAdd(&ex.pos[ex.dst[e]], 1);
        ex.esrcS[p] = ex.src[e];
        ex.eaS[p] = *(const float2*)(ex.ea + (size_t)e * 2);
      }
    }
    return;
  }

  // ---- job select
  const u16* jA1 = A1; const u16* jA2 = A2; const u16* jBT = BT;
  const float* jbias = bias; u16* jCb = Cb; int jM = M;
  if (bx >= j2.xSplit) {
    bx -= j2.xSplit;
    jA1 = j2.A1; jA2 = j2.A2; jBT = j2.BT;
    jbias = j2.bias; jCb = j2.Cb; jM = j2.M;
  }
  const int bm = bx * 128;
  const int bn = ny * 128;

  const int wr = (wid >> 1) * 64;
  const int wc = (wid & 1) * 64;

  f32x4 acc[4][4];
#pragma unroll
  for (int m = 0; m < 4; ++m)
#pragma unroll
    for (int n = 0; n < 4; ++n) acc[m][n] = (f32x4){0.f, 0.f, 0.f, 0.f};

  const int srow = lane >> 3;  // 0..7
  const int slot = lane & 7;   // 16B slot in 128B row
  const size_t astride = (jA2 != nullptr) ? 512 : (size_t)K;

  for (int k0 = 0; k0 < K; k0 += 64) {
    const u16* Ap = jA1;
    int kof = k0;
    if (jA2 != nullptr && k0 >= 512) { Ap = jA2; kof = k0 - 512; }
#pragma unroll
    for (int t = 0; t < 4; ++t) {
      const int inst = wid * 4 + t;
      const int row  = inst * 8 + srow;
      const int scol = ((slot ^ (row & 7)) << 4);    // byte offset in bf16 row
      const int ar   = min(bm + row, jM - 1);
      if constexpr (A_F32) {
        const float* srcf = (const float*)Ap + (size_t)ar * astride + kof + (scol >> 1);
        const float4 v0 = *reinterpret_cast<const float4*>(srcf);
        const float4 v1 = *reinterpret_cast<const float4*>(srcf + 4);
        u16x8 pk;
        pk[0] = f2bf(v0.x); pk[1] = f2bf(v0.y); pk[2] = f2bf(v0.z); pk[3] = f2bf(v0.w);
        pk[4] = f2bf(v1.x); pk[5] = f2bf(v1.y); pk[6] = f2bf(v1.z); pk[7] = f2bf(v1.w);
        *reinterpret_cast<u16x8*>((char*)As + inst * 1024 + lane * 16) = pk;
      } else {
        gload_lds16((const char*)Ap + ((size_t)ar * astride + kof) * 2 + scol,
                    (char*)As + inst * 1024);
      }
    }
#pragma unroll
    for (int t = 0; t < 4; ++t) {
      const int inst = wid * 4 + t;
      const int row  = inst * 8 + srow;
      const int scol = ((slot ^ (row & 7)) << 4);
      const int bc   = min(bn + row, N - 1);
      gload_lds16((const char*)jBT + ((size_t)bc * K + k0) * 2 + scol,
                  (char*)Bs + inst * 1024);
    }
    asm volatile("s_waitcnt vmcnt(0)" ::: "memory");
    __syncthreads();

#pragma unroll
    for (int kk = 0; kk < 2; ++kk) {
      bf16x8 af[4], bfr[4];
#pragma unroll
      for (int m = 0; m < 4; ++m) {
        const int r = wr + m * 16 + (lane & 15);
        const int s = kk * 4 + (lane >> 4);
        af[m] = *(const bf16x8*)((const char*)As + r * 128 + ((s ^ (r & 7)) << 4));
      }
#pragma unroll
      for (int n = 0; n < 4; ++n) {
        const int c = wc + n * 16 + (lane & 15);
        const int s = kk * 4 + (lane >> 4);
        bfr[n] = *(const bf16x8*)((const char*)Bs + c * 128 + ((s ^ (c & 7)) << 4));
      }
      // operand-swapped: accumulates the C^T fragment (same sums, new layout)
#pragma unroll
      for (int m = 0; m < 4; ++m)
#pragma unroll
        for (int n = 0; n < 4; ++n)
          acc[m][n] = __builtin_amdgcn_mfma_f32_16x16x32_bf16(bfr[n], af[m],
                                                              acc[m][n], 0, 0, 0);
    }
    __syncthreads();
  }

  // ---- epilogue: thread holds C[r, c0..c0+3]
#pragma unroll
  for (int m = 0; m < 4; ++m) {
    const int r = bm + wr + m * 16 + (lane & 15);
    if (r >= jM) continue;
#pragma unroll
    for (int n = 0; n < 4; ++n) {
      const int c0 = bn + wc + n * 16 + ((lane >> 4) << 2);
      if (c0 >= N) continue;  // N%4==0 -> whole 4-pack in range
      float4 bv = make_float4(0.f, 0.f, 0.f, 0.f);
      if (jbias != nullptr) bv = *reinterpret_cast<const float4*>(jbias + c0);
      float v0 = acc[m][n][0] + bv.x;
      float v1 = acc[m][n][1] + bv.y;
      float v2 = acc[m][n][2] + bv.z;
      float v3 = acc[m][n][3] + bv.w;
      if (WRITE_F32) {
        float4 o; o.x = v0; o.y = v1; o.z = v2; o.w = v3;
        *reinterpret_cast<float4*>(Cf + (size_t)r * ldc + c0) = o;
      }
      if (WRITE_BF16) {
        u16* dstp = jCb;
        int c = c0;
        if (Cb2 != nullptr && c0 >= nsplit) { dstp = Cb2; c = c0 - nsplit; }
        ushort4 o;
        o.x = f2bf(v0); o.y = f2bf(v1); o.z = f2bf(v2); o.w = f2bf(v3);
        *reinterpret_cast<ushort4*>(dstp + (size_t)r * ldc + c) = o;
      }
    }
  }
}

// ---------------------------------------------------------------------------
// Fused per-node GATv2 attention + residual + LayerNorm + ReLU.
// (R15/R17/R18/R21 kernel verbatim — best measured: 65.5 us.)
// ---------------------------------------------------------------------------
__global__ __launch_bounds__(256) void gat_fused_kernel(
    const u16* __restrict__ xl, const u16* __restrict__ xr,
    const int* __restrict__ esrcS, const float2* __restrict__ eaS,
    const int* __restrict__ offs, const float* __restrict__ We,
    const float* __restrict__ att, const float* __restrict__ bias,
    const float* __restrict__ lng, const float* __restrict__ lnb,
    const u16* __restrict__ resid, u16* __restrict__ hb) {
  __shared__ float accLDS[4][512];
  __shared__ float wsLDS[4];
  const int wid = threadIdx.x >> 6, lane = threadIdx.x & 63;
  const int n = blockIdx.x;
  const int d8 = lane * 8;

  float r8[8], w0[8], w1[8], a06[8], a04[8];
  {
    const u16x8 rv = *(const u16x8*)(xr + (size_t)n * kD + d8);
#pragma unroll
    for (int i = 0; i < 8; ++i) {
      r8[i] = bf2f(rv[i]);
      w0[i] = We[d8 + i];
      w1[i] = We[kD + d8 + i];
      const float a = att[d8 + i];
      a06[i] = 0.6f * a;      // lrelu(m) = 0.6m + 0.4|m| for slope 0.2
      a04[i] = 0.4f * a;
    }
  }

  float acc[8];
#pragma unroll
  for (int j = 0; j < 8; ++j) acc[j] = 0.f;
  float l_run = 0.f;

  const int beg = offs[n], end = offs[n + 1];
  const int cnt = end - beg;
  const int q = cnt >> 2, r = cnt & 3;
  const int myCnt = q + ((wid < r) ? 1 : 0);
  const int myBeg = beg + wid * q + min(wid, r);

  int sv = 0;
  float2 e2 = make_float2(0.f, 0.f);
  if (lane < myCnt) {
    sv = esrcS[myBeg + lane];
    e2 = eaS[myBeg + lane];
  }

  for (int i = 0; i < myCnt; i += 4) {
    const int k = myCnt - i;  // wave-uniform guards
    u16x8 rows[4];
#pragma unroll
    for (int t = 0; t < 4; ++t)
      if (t < k)
        rows[t] = *(const u16x8*)(xl + (size_t)__shfl(sv, i + t) * kD + d8);
    float s[4];
#pragma unroll
    for (int t = 0; t < 4; ++t) {
      s[t] = 0.f;
      if (t < k) {
        const float ex = __shfl(e2.x, i + t), ey = __shfl(e2.y, i + t);
#pragma unroll
        for (int j = 0; j < 8; ++j) {
          const float m = bf2f(rows[t][j]) + r8[j] + ex * w0[j] + ey * w1[j];
          s[t] += a06[j] * m + a04[j] * fabsf(m);
        }
      }
    }
#pragma unroll
    for (int off = 32; off > 0; off >>= 1)
#pragma unroll
      for (int t = 0; t < 4; ++t)
        if (t < k) s[t] += __shfl_xor(s[t], off);
    float qv[4];
    float ws = 0.f;
#pragma unroll
    for (int t = 0; t < 4; ++t) {
      qv[t] = (t < k) ? __expf(s[t]) : 0.f;
      ws += qv[t];
    }
    l_run += ws;
#pragma unroll
    for (int j = 0; j < 8; ++j) {
      float v = acc[j];
#pragma unroll
      for (int t = 0; t < 4; ++t)
        if (t < k) v += qv[t] * bf2f(rows[t][j]);
      acc[j] = v;
    }
  }

  if (lane == 0) wsLDS[wid] = l_run;
#pragma unroll
  for (int j = 0; j < 8; ++j) accLDS[wid][j * 64 + lane] = acc[j];
  __syncthreads();

  if (wid == 0) {
    const float l = wsLDS[0] + wsLDS[1] + wsLDS[2] + wsLDS[3];
    const float inv = 1.f / (l > 0.f ? l : 1.f);
    float aT[8];
#pragma unroll
    for (int j = 0; j < 8; ++j)
      aT[j] = accLDS[0][j * 64 + lane] + accLDS[1][j * 64 + lane] +
              accLDS[2][j * 64 + lane] + accLDS[3][j * 64 + lane];

    float xv[8];
    float sum = 0.f, sq = 0.f;
    {
      const u16x8 hv8 = *(const u16x8*)(resid + (size_t)n * kD + d8);
#pragma unroll
      for (int j = 0; j < 8; ++j) {
        xv[j] = bf2f(hv8[j]) + aT[j] * inv + bias[d8 + j];
        sum += xv[j];
        sq  += xv[j] * xv[j];
      }
    }
#pragma unroll
    for (int off = 32; off > 0; off >>= 1) {
      sum += __shfl_xor(sum, off);
      sq  += __shfl_xor(sq, off);
    }
    const float mean = sum * (1.f / kD);
    const float var  = sq * (1.f / kD) - mean * mean;
    const float rs = rsqrtf(var + kLnEps);
    u16x8 pk;
#pragma unroll
    for (int j = 0; j < 8; ++j) {
      const float y = fmaxf((xv[j] - mean) * rs * lng[d8 + j] + lnb[d8 + j], 0.f);
      pk[j] = f2bf(y);
    }
    *(u16x8*)(hb + (size_t)n * kD + d8) = pk;
  }
}

// ---------------------------------------------------------------------------
// Batched transpose (z<10): dst[n][k] = bf16(src[k][n]); N=512 cols each.
// z==10: concat bias build + zero counts/done (re-zeroed each replay).
// ---------------------------------------------------------------------------
struct TxJobs {
  const float* src[10];
  u16* dst[10];
  int K[10];
  const float* bl; const float* br; float* catB;
  int* counts; int* done;
};

__global__ __launch_bounds__(256) void transpose_all_kernel(TxJobs jobs) {
  const int z = blockIdx.z;
  if (z == 10) {
    const int lid = (blockIdx.y * 32 + blockIdx.x) * 256 + threadIdx.x;
    if (lid < 3 * 1024) {
      const int k = lid >> 10, j = lid & 1023;
      jobs.catB[lid] = (j < 512) ? jobs.bl[k * 512 + j] : jobs.br[k * 512 + j - 512];
    }
    const int cid = lid - 3 * 1024;
    if (cid >= 0 && cid < kN) jobs.counts[cid] = 0;
    if (cid == kN) jobs.done[0] = 0;
    return;
  }
  const int K = jobs.K[z];
  const int k0 = blockIdx.x * 32;
  if (k0 >= K) return;
  const int n0 = blockIdx.y * 32;
  const float* W = jobs.src[z];
  u16* WT = jobs.dst[z];
  __shared__ float t[32][33];
  const int lx = threadIdx.x & 31, ly = threadIdx.x >> 5;  // 32 x 8
#pragma unroll
  for (int r = 0; r < 32; r += 8)
    t[ly + r][lx] = W[(size_t)(k0 + ly + r) * 512 + n0 + lx];
  __syncthreads();
#pragma unroll
  for (int r = 0; r < 32; r += 8)
    WT[(size_t)(n0 + ly + r) * K + k0 + lx] = f2bf(t[lx][ly + r]);
}

// ---------------------------------------------------------------------------
// Fused scan: 40 blocks do local scans; the LAST block (device-scope atomic
// ticket, validated R20) computes the top scan AND materializes offs/pos.
// ---------------------------------------------------------------------------
__global__ __launch_bounds__(256) void scan_fused_kernel(
    int* __restrict__ counts, int* __restrict__ offsL,
    int* __restrict__ bsum, int* __restrict__ done,
    int* __restrict__ offs, int* __restrict__ pos) {
  __shared__ int buf[256];
  __shared__ int boffS[kScanBlocks];
  __shared__ int lastFlag;
  const int tid = threadIdx.x, bid = blockIdx.x;
  const int i = bid * 256 + tid;
  const int v = (i < kN) ? counts[i] : 0;
  buf[tid] = v;
  __syncthreads();
  for (int off = 1; off < 256; off <<= 1) {
    const int t = (tid >= off) ? buf[tid - off] : 0;
    __syncthreads();
    buf[tid] += t;
    __syncthreads();
  }
  if (i < kN) offsL[i] = buf[tid] - v;  // block-local exclusive
  if (tid == 255) bsum[bid] = buf[255];
  __syncthreads();
  __threadfence();            // device-scope release
  if (tid == 0) lastFlag = (atomicAdd(done, 1) == kScanBlocks - 1);
  __syncthreads();
  if (!lastFlag) return;
  __threadfence();            // acquire side
  if (tid < 64) {
    const int b = (tid < kScanBlocks) ? atomicAdd(&bsum[tid], 0) : 0;
    int incl = b;
#pragma unroll
    for (int off = 1; off < 64; off <<= 1) {
      const int t = __shfl_up(incl, off);
      if (tid >= off) incl += t;
    }
    if (tid < kScanBlocks) boffS[tid] = incl - b;
  }
  __syncthreads();
  // materialize offs/pos (forced-L2 reads of other blocks' offsL)
  for (int j = tid; j < kN; j += 256) {
    const int o = atomicAdd(&offsL[j], 0) + boffS[j >> 8];
    offs[j] = o;
    pos[j] = o;
  }
  if (tid == 0) offs[kN] = kE;
}

}  // namespace

extern "C" void kernel_launch(void* const* d_in, const int* in_sizes, int n_in,
                              void* d_out, int out_size, void* d_ws, size_t ws_size,
                              hipStream_t stream) {
  const float* x         = (const float*)d_in[0];
  const float* edge_attr = (const float*)d_in[1];
  const float* emb_inv_W = (const float*)d_in[2];
  const float* emb_inv_b = (const float*)d_in[3];
  const float* emb_org_W = (const float*)d_in[4];
  const float* emb_org_b = (const float*)d_in[5];
  const float* gat_Wl    = (const float*)d_in[6];
  const float* gat_bl    = (const float*)d_in[7];
  const float* gat_Wr    = (const float*)d_in[8];
  const float* gat_br    = (const float*)d_in[9];
  const float* gat_We    = (const float*)d_in[10];
  const float* gat_att   = (const float*)d_in[11];
  const float* gat_bias  = (const float*)d_in[12];
  const float* ln_g      = (const float*)d_in[13];
  const float* ln_b      = (const float*)d_in[14];
  const float* lin0_W    = (const float*)d_in[15];
  const float* lin0_b    = (const float*)d_in[16];
  const float* lin1_W    = (const float*)d_in[17];
  const float* lin1_b    = (const float*)d_in[18];
  const int*   edge_idx  = (const int*)d_in[19];
  const int* src = edge_idx;
  const int* dst = edge_idx + kE;
  float* out = (float*)d_out;

  // ---- workspace layout (~58 MB) ----
  float* catB = (float*)d_ws;          // [3,1024] concat gat biases
  u16* hb0  = (u16*)(catB + 3072);     // [N,D] bf16 initial embedding (residual 0)
  u16* hb   = hb0 + kND;               // [N,D] bf16 running h (residual stream)
  u16* xlB  = hb + kND;                // [N,D]
  u16* xrB  = xlB + kND;               // [N,D]
  u16* y0b  = xrB + kND;               // [4000,512]
  u16* y1b  = y0b + kNinv * kD;        // [3000,512]
  u16* embInvT = y1b + kNunk * kD;     // [512,512]
  u16* embOrgT = embInvT + 262144;
  u16* WlrT    = embOrgT + 262144;     // 3 x [1024,512]
  u16* lin0T   = WlrT + 3 * 524288;    // [512,1024]
  u16* lin1T   = lin0T + 524288;
  int* counts  = (int*)(lin1T + 524288);  // [N]
  int* offsL   = counts + kN;             // [N] block-local exclusive scan
  int* offs    = offsL + kN;              // [N+1]
  int* pos     = offs + kN + 1;           // [N]
  int* bsum    = pos + kN;                // [kScanBlocks]
  int* done    = bsum + kScanBlocks;      // [1]
  int* esrcS   = done + 1;                // [E] src in dst-sorted order
  float2* eaS  = (float2*)(esrcS + kE);   // [E] edge_attr in dst-sorted order

  const dim3 blk(256);
  auto cdiv = [](int a, int b) { return (a + b - 1) / b; };
  Job2 jNone{};
  jNone.xSplit = 0x7FFFFFFF;
  Extra exNone{};
  exNone.mode = 0;

  // ---- 0. setup: batched weight transpose + (z=10) catbias + zeroing
  {
    TxJobs j;
    j.src[0] = emb_inv_W;  j.dst[0] = embInvT;  j.K[0] = 512;
    j.src[1] = emb_org_W;  j.dst[1] = embOrgT;  j.K[1] = 512;
    for (int k = 0; k < 3; ++k) {
      j.src[2 + k] = gat_Wl + (size_t)k * kD * kD;
      j.dst[2 + k] = WlrT + (size_t)k * 524288;            // rows 0..511
      j.K[2 + k] = 512;
      j.src[5 + k] = gat_Wr + (size_t)k * kD * kD;
      j.dst[5 + k] = WlrT + (size_t)k * 524288 + 262144;   // rows 512..1023
      j.K[5 + k] = 512;
    }
    j.src[8] = lin0_W; j.dst[8] = lin0T; j.K[8] = 1024;
    j.src[9] = lin1_W; j.dst[9] = lin1T; j.K[9] = 1024;
    j.bl = gat_bl; j.br = gat_br; j.catB = catB;
    j.counts = counts; j.done = done;
    transpose_all_kernel<<<dim3(32, 16, 11), blk, 0, stream>>>(j);
  }

  // ---- 1. embeddings (merged pair; fp32 A) + COUNT piggyback row
  {
    Job2 je;
    je.A1 = (const u16*)(x + (size_t)kNinv * kD);
    je.A2 = nullptr;
    je.BT = embOrgT;
    je.bias = emb_org_b;
    je.Cb = hb0 + (size_t)kNinv * kD;
    je.M = kN - kNinv;
    je.xSplit = cdiv(kNinv, 128);  // 32
    Extra ec{};
    ec.mode = 1; ec.dst = dst; ec.counts = counts;
    const int gx = je.xSplit + cdiv(kN - kNinv, 128);  // 32 + 47
    gemm_bf16<false, true, true><<<dim3(gx, 5), blk, 0, stream>>>(
        (const u16*)x, nullptr, embInvT, emb_inv_b, nullptr, hb0, nullptr, 0,
        kNinv, kD, kD, kD, je, ec);
  }

  // ---- 2. fused scan + offs/pos materialization (one dispatch)
  scan_fused_kernel<<<dim3(kScanBlocks), blk, 0, stream>>>(counts, offsL, bsum,
                                                           done, offs, pos);

  // ---- 3. GAT layers; layer 0's lr-GEMM carries the SCATTER piggyback row
  for (int k = 0; k < 3; ++k) {
    const u16* hIn = (k == 0) ? hb0 : hb;
    Extra ex = exNone;
    int gy = 8;
    if (k == 0) {
      ex.mode = 2; ex.dst = dst; ex.src = src; ex.ea = edge_attr;
      ex.pos = pos; ex.esrcS = esrcS; ex.eaS = eaS;
      gy = 9;
    }
    gemm_bf16<false, true, false><<<dim3(cdiv(kN, 128), gy), blk, 0, stream>>>(
        hIn, nullptr, WlrT + (size_t)k * 524288, catB + k * 1024,
        nullptr, xlB, xrB, 512, kN, 1024, kD, kD, jNone, ex);
    gat_fused_kernel<<<dim3(kN), blk, 0, stream>>>(
        xlB, xrB, esrcS, eaS, offs,
        gat_We + (size_t)k * 2 * kD, gat_att + (size_t)k * kD,
        gat_bias + (size_t)k * kD, ln_g + (size_t)k * kD,
        ln_b + (size_t)k * kD, hIn, hb);
  }

  // ---- 4. heads (merged pair) via A-split ([hb0 | hb] along K): y0, y1
  {
    const size_t off = (size_t)(kN - kNunk) * kD;
    Job2 jh;
    jh.A1 = hb0 + off;
    jh.A2 = hb + off;
    jh.BT = lin1T;
    jh.bias = lin1_b;
    jh.Cb = y1b;
    jh.M = kNunk;
    jh.xSplit = cdiv(kNinv, 128);  // 32
    const int gx = jh.xSplit + cdiv(kNunk, 128);  // 32 + 24
    gemm_bf16<false, true, false><<<dim3(gx, 4), blk, 0, stream>>>(
        hb0, hb, lin0T, lin0_b, nullptr, y0b, nullptr, 0,
        kNinv, kD, 2 * kD, kD, jh, exNone);
  }

  // ---- 5. out = y0 @ y1^T  [4000,3000]
  gemm_bf16<true, false, false><<<dim3(cdiv(kNinv, 128), cdiv(kNunk, 128)), blk, 0,
                                  stream>>>(
      y0b, nullptr, y1b, nullptr, out, nullptr, nullptr, 0,
      kNinv, kNunk, kD, kNunk, jNone, exNone);
}